// Round 7
// baseline (247.046 us; speedup 1.0000x reference)
//
#include <hip/hip_runtime.h>
#include <hip/hip_bf16.h>

typedef short bf16x8 __attribute__((ext_vector_type(8)));
typedef short u16x4v __attribute__((ext_vector_type(4)));
typedef float f32x4  __attribute__((ext_vector_type(4)));
typedef unsigned short u16;
typedef unsigned int   u32;

#define NB   2
#define NS   2048
#define ND   1024
#define NH   16
#define NHD  64
#define N3   3072
#define NM   4096   /* B*S */

__device__ __forceinline__ u16 f2bf(float f) {
    u32 u;
    __builtin_memcpy(&u, &f, 4);
    u += 0x7fffu + ((u >> 16) & 1u);
    return (u16)(u >> 16);
}
__device__ __forceinline__ float bf2f(u16 x) {
    u32 u = ((u32)x) << 16;
    float f;
    __builtin_memcpy(&f, &u, 4);
    return f;
}
// Load 8 consecutive f32, convert RTNE to a bf16x8 fragment.
__device__ __forceinline__ bf16x8 load8f(const float* f) {
    float4 a = *(const float4*)f;
    float4 b = *(const float4*)(f + 4);
    bf16x8 r;
    r[0] = (short)f2bf(a.x); r[1] = (short)f2bf(a.y);
    r[2] = (short)f2bf(a.z); r[3] = (short)f2bf(a.w);
    r[4] = (short)f2bf(b.x); r[5] = (short)f2bf(b.y);
    r[6] = (short)f2bf(b.z); r[7] = (short)f2bf(b.w);
    return r;
}
// Async global->LDS, 16B per lane. LDS dest = wave-uniform base + lane*16.
__device__ __forceinline__ void gload_lds16(const void* g, void* l) {
    __builtin_amdgcn_global_load_lds(
        (const __attribute__((address_space(1))) u32*)g,
        (__attribute__((address_space(3))) u32*)l, 16, 0, 0);
}

// ---------------------------------------------------------------------------
// Kernel 0: prep — X f32->bf16 (blocks [0,2048)), Wqkv transpose+cvt
// ([2048,5120)), Wout transpose+cvt ([5120,6144)).
// ---------------------------------------------------------------------------
__global__ __launch_bounds__(256) void prep_cvt(
    const float* __restrict__ X, u16* __restrict__ Xb,
    const float* __restrict__ Wqkv, u16* __restrict__ WqkvT,
    const float* __restrict__ Wout, u16* __restrict__ WoutT)
{
    __shared__ float t[32][33];
    const int b = blockIdx.x;
    if (b < 2048) {
        const int i = (b * 256 + threadIdx.x) * 8;
        *(bf16x8*)(Xb + i) = load8f(X + i);
        return;
    }
    const float* in; u16* outp; int R, C, tIdx;
    if (b < 5120) { in = Wqkv; outp = WqkvT; R = ND; C = N3; tIdx = b - 2048; }
    else          { in = Wout; outp = WoutT; R = ND; C = ND; tIdx = b - 5120; }
    const int nbc = C >> 5;
    const int r0 = (tIdx / nbc) << 5;
    const int c0 = (tIdx % nbc) << 5;
    const int tr = threadIdx.x >> 3, tc = (threadIdx.x & 7) << 2;
    const float4 v = *(const float4*)(in + (size_t)(r0 + tr) * C + c0 + tc);
    t[tr][tc] = v.x; t[tr][tc + 1] = v.y; t[tr][tc + 2] = v.z; t[tr][tc + 3] = v.w;
    __syncthreads();
    u16x4v ov;
    ov[0] = (short)f2bf(t[tc + 0][tr]); ov[1] = (short)f2bf(t[tc + 1][tr]);
    ov[2] = (short)f2bf(t[tc + 2][tr]); ov[3] = (short)f2bf(t[tc + 3][tr]);
    *(u16x4v*)(outp + (size_t)(c0 + tr) * R + r0 + tc) = ov;
}

// ---------------------------------------------------------------------------
// Kernel 1: QKV projection, 128x128 tile / BK=64. V-class blocks route the
// vT_ws store through a 32KB LDS transpose (coalesced 128B global writes).
// ---------------------------------------------------------------------------
template<bool BF>
__global__ __launch_bounds__(256) void qkv_gemm(
    const float* __restrict__ Xf, const u16* __restrict__ Xb,
    const float* __restrict__ Wf, const u16* __restrict__ WbT,
    const float* __restrict__ bias,
    u16* __restrict__ q_ws, u16* __restrict__ vT_ws, u16* __restrict__ k_ws,
    float* __restrict__ k_out, float* __restrict__ v_out)
{
    __shared__ __align__(16) u16 SM[128 * 128];   // staging (As|Bs) / transpose
    u16* As = SM;                                 // 128x64
    u16* Bs = SM + 8192;                          // 128x64

    const int bm = blockIdx.x & 31;        // 32 M-tiles
    const int bn = blockIdx.x >> 5;        // 24 N-tiles
    const int m0 = bm * 128, n0 = bn * 128;
    const int tid = threadIdx.x;
    const int lane = tid & 63, wv = tid >> 6;
    const int wm = wv >> 1, wn = wv & 1;
    const int li = lane & 15, lg = lane >> 4;

    f32x4 acc[4][4];
    #pragma unroll
    for (int i = 0; i < 4; ++i)
        #pragma unroll
        for (int j = 0; j < 4; ++j)
            acc[i][j] = (f32x4){0.f, 0.f, 0.f, 0.f};

    for (int k0 = 0; k0 < ND; k0 += 64) {
        if constexpr (BF) {
            #pragma unroll
            for (int i = 0; i < 4; ++i) {
                const int r0 = (i * 4 + wv) * 8;
                gload_lds16(Xb  + (size_t)(m0 + r0 + (lane >> 3)) * ND + k0 + (lane & 7) * 8, &As[r0 * 64]);
                gload_lds16(WbT + (size_t)(n0 + r0 + (lane >> 3)) * ND + k0 + (lane & 7) * 8, &Bs[r0 * 64]);
            }
        } else {
            #pragma unroll
            for (int i = 0; i < 4; ++i) {
                const int row = 32 * i + (tid >> 3), col = (tid & 7) * 8;
                *(bf16x8*)(&As[row * 64 + col]) = load8f(Xf + (size_t)(m0 + row) * ND + k0 + col);
            }
            #pragma unroll
            for (int i = 0; i < 4; ++i) {
                const int krow = 16 * i + (tid >> 4), ncol = (tid & 15) * 8;
                bf16x8 bv = load8f(Wf + (size_t)(k0 + krow) * N3 + n0 + ncol);
                #pragma unroll
                for (int jj = 0; jj < 8; ++jj)
                    Bs[(ncol + jj) * 64 + krow] = (u16)bv[jj];
            }
        }
        __syncthreads();

        bf16x8 a[4][2], b[4][2];
        #pragma unroll
        for (int i = 0; i < 4; ++i)
            #pragma unroll
            for (int kk = 0; kk < 2; ++kk)
                a[i][kk] = *(const bf16x8*)(&As[(wm * 64 + i * 16 + li) * 64 + kk * 32 + lg * 8]);
        #pragma unroll
        for (int j = 0; j < 4; ++j)
            #pragma unroll
            for (int kk = 0; kk < 2; ++kk)
                b[j][kk] = *(const bf16x8*)(&Bs[(wn * 64 + j * 16 + li) * 64 + kk * 32 + lg * 8]);
        #pragma unroll
        for (int i = 0; i < 4; ++i)
            #pragma unroll
            for (int j = 0; j < 4; ++j) {
                acc[i][j] = __builtin_amdgcn_mfma_f32_16x16x32_bf16(a[i][0], b[j][0], acc[i][j], 0, 0, 0);
                acc[i][j] = __builtin_amdgcn_mfma_f32_16x16x32_bf16(a[i][1], b[j][1], acc[i][j], 0, 0, 0);
            }
        __syncthreads();
    }

    const int cls = bn >> 3;   // 0=Q, 1=K, 2=V
    if (cls == 2) {
        // f32 output direct; bf16 into LDS transposed [n][m] (XOR-swizzled m)
        #pragma unroll
        for (int i = 0; i < 4; ++i) {
          #pragma unroll
          for (int j = 0; j < 4; ++j) {
            const int gn = n0 + wn * 64 + j * 16 + li;
            const float bval = bias[gn];
            const int c = gn & 1023, h = c >> 6, d = c & 63;
            const int n_ = wn * 64 + j * 16 + li;
            #pragma unroll
            for (int r = 0; r < 4; ++r) {
                const int gm = m0 + wm * 64 + i * 16 + lg * 4 + r;
                const int b_ = gm >> 11, sI = gm & 2047;
                const float v = acc[i][j][r] + bval;
                v_out[(((size_t)(b_ * NH + h)) * NS + sI) * NHD + d] = v;
                const int m_ = wm * 64 + i * 16 + lg * 4 + r;
                SM[n_ * 128 + (m_ ^ ((n_ & 7) << 3))] = f2bf(v);
            }
          }
        }
        __syncthreads();
        const int nrow = tid >> 1, mh = tid & 1;
        const int cdx = (n0 - 2048) + nrow;           // V col 0..1023
        const int hh = cdx >> 6, d = cdx & 63;
        const int b_ = m0 >> 11;
        const int s0 = (m0 & 2047) + mh * 64;
        u16* dst = vT_ws + (((size_t)(b_ * NH + hh)) * NHD + d) * NS + s0;
        #pragma unroll
        for (int c8 = 0; c8 < 8; ++c8) {
            const int m_ = mh * 64 + c8 * 8;
            *(bf16x8*)(dst + c8 * 8) =
                *(const bf16x8*)(&SM[nrow * 128 + (m_ ^ ((nrow & 7) << 3))]);
        }
    } else {
        #pragma unroll
        for (int i = 0; i < 4; ++i) {
          #pragma unroll
          for (int j = 0; j < 4; ++j) {
            const int gn = n0 + wn * 64 + j * 16 + li;
            const float bval = bias[gn];
            const int c = gn & 1023, h = c >> 6, d = c & 63;
            #pragma unroll
            for (int r = 0; r < 4; ++r) {
                const int gm = m0 + wm * 64 + i * 16 + lg * 4 + r;
                const int b_ = gm >> 11, sI = gm & 2047;
                const float v = acc[i][j][r] + bval;
                const size_t hidx = (((size_t)(b_ * NH + h)) * NS + sI) * NHD + d;
                if (cls == 0) {
                    q_ws[hidx] = f2bf(v * 0.125f);
                } else {
                    k_out[hidx] = v;
                    k_ws[hidx] = f2bf(v);
                }
            }
          }
        }
    }
}

// ---------------------------------------------------------------------------
// Kernel 2: causal flash attention, split-K over 1024 uniform blocks.
// Per bh (32 total), 32 blocks: rem<8  : cat-A pair (p,15-p), keys[0,1024),
//   final write; rem<24: cat-B single upper tile, keys[0,1024), partial-1;
//   else: cat-C pair over keys[1024,2048), partial-2. ~16-17 half-tile units
//   per block, all uniform. LDS = 40960B -> 4 blocks/CU.
// ---------------------------------------------------------------------------
__global__ __launch_bounds__(256, 4) void attn_fwd(
    u16* __restrict__ q_all, const u16* __restrict__ k_all,
    const u16* __restrict__ vT,
    u16* __restrict__ o1, u16* __restrict__ o2,
    float2* __restrict__ ml1, float2* __restrict__ ml2)
{
    __shared__ __align__(16) u16 Ks[2][64 * 64];
    __shared__ __align__(16) u16 Vs[2][64 * 64];
    __shared__ __align__(16) u16 Pl[4][16 * 64];   // XOR-swizzled, shared h

    const int tid = threadIdx.x;
    const int wv = tid >> 6, lane = tid & 63;
    const int li = lane & 15, lg = lane >> 4;
    const int bid = blockIdx.x;                  // 1024
    const int wg  = (bid & 7) * 128 + (bid >> 3);
    const int bh  = wg >> 5;
    const int rem = wg & 31;

    int qtA, qtB, ntA, ntB, koff, mode;
    if (rem < 8)       { qtA = rem;      qtB = 15 - rem;      ntA = rem + 1;  ntB = 16 - rem;  koff = 0;    mode = 0; }
    else if (rem < 24) { qtA = rem + 8;  qtB = rem + 8;       ntA = 0;        ntB = 16;        koff = 0;    mode = 1; }
    else { const int u = rem - 24; qtA = 16 + u; qtB = 31 - u; ntA = u + 1;   ntB = 16 - u;    koff = 1024; mode = 2; }

    const int q0A = qtA * 64 + wv * 16, q0B = qtB * 64 + wv * 16;

    u16* qp = q_all + (size_t)bh * NS * NHD;
    const u16* kpo = k_all + (size_t)bh * NS * NHD + (size_t)koff * NHD;
    const u16* vpo = vT + (size_t)bh * NHD * NS + koff;

    const int rl = lane >> 3;
    const int gsw = ((lane & 7) * 16) ^ (rl << 4);  // pre-swizzled byte col
    const int rs = (li & 7) << 3;                   // u16-unit read swizzle

    bf16x8 aq[2][2];
    aq[0][0] = *(const bf16x8*)(qp + (size_t)(q0A + li) * NHD + lg * 8);
    aq[0][1] = *(const bf16x8*)(qp + (size_t)(q0A + li) * NHD + 32 + lg * 8);
    aq[1][0] = *(const bf16x8*)(qp + (size_t)(q0B + li) * NHD + lg * 8);
    aq[1][1] = *(const bf16x8*)(qp + (size_t)(q0B + li) * NHD + 32 + lg * 8);

    f32x4 o[2][4], ls[2];
    #pragma unroll
    for (int h = 0; h < 2; ++h) {
        ls[h] = (f32x4){0.f, 0.f, 0.f, 0.f};
        #pragma unroll
        for (int nf = 0; nf < 4; ++nf) o[h][nf] = (f32x4){0.f, 0.f, 0.f, 0.f};
    }
    float m = 4.0f;   // deferred-max baseline; exact (common scale of O and l)

    const short onb = (short)0x3F80;
    const bf16x8 ones = {onb, onb, onb, onb, onb, onb, onb, onb};

    #define STAGE(B, KB) do {                                                           \
        _Pragma("unroll")                                                               \
        for (int i_ = 0; i_ < 2; ++i_) {                                                \
            const int row_ = 16 * wv + 8 * i_;                                          \
            gload_lds16((const char*)(kpo + (size_t)((KB) + row_ + rl) * NHD) + gsw,    \
                        &Ks[B][row_ * 64]);                                             \
            gload_lds16((const char*)(vpo + (size_t)(row_ + rl) * NS + (KB)) + gsw,     \
                        &Vs[B][row_ * 64]);                                             \
        } } while (0)

    STAGE(0, 0);
    __syncthreads();

    int buf = 0;
    for (int kt = 0; kt < ntB; ++kt) {
        const int kb = kt * 64;
        if (kt + 1 < ntB) STAGE(buf ^ 1, kb + 64);

        const u16* K = Ks[buf];
        const u16* V = Vs[buf];
        const bool actA = (kt < ntA);

        f32x4 s[4][2];
        __builtin_amdgcn_s_setprio(1);
        #pragma unroll
        for (int kq = 0; kq < 4; ++kq) {
            const u16* Kr = K + (kq * 16 + li) * 64;
            const bf16x8 b0 = *(const bf16x8*)(Kr + ((lg * 8) ^ rs));
            const bf16x8 b1 = *(const bf16x8*)(Kr + ((lg * 8 + 32) ^ rs));
            f32x4 t1 = (f32x4){0.f, 0.f, 0.f, 0.f};
            t1 = __builtin_amdgcn_mfma_f32_16x16x32_bf16(aq[1][0], b0, t1, 0, 0, 0);
            s[kq][1] = __builtin_amdgcn_mfma_f32_16x16x32_bf16(aq[1][1], b1, t1, 0, 0, 0);
            if (actA) {
                f32x4 t0 = (f32x4){0.f, 0.f, 0.f, 0.f};
                t0 = __builtin_amdgcn_mfma_f32_16x16x32_bf16(aq[0][0], b0, t0, 0, 0, 0);
                s[kq][0] = __builtin_amdgcn_mfma_f32_16x16x32_bf16(aq[0][1], b1, t0, 0, 0, 0);
            }
        }
        __builtin_amdgcn_s_setprio(0);

        // deferred max: per-lane tree + wave vote; reduce only on trigger
        float mx = s[0][1][0];
        #pragma unroll
        for (int kq = 0; kq < 4; ++kq)
            #pragma unroll
            for (int r = 0; r < 4; ++r) {
                mx = fmaxf(mx, s[kq][1][r]);
                if (actA) mx = fmaxf(mx, s[kq][0][r]);
            }
        if (__any(mx > m)) {
            #pragma unroll
            for (int dd = 1; dd < 64; dd <<= 1)
                mx = fmaxf(mx, __shfl_xor(mx, dd, 64));
            const float corr = __expf(m - mx);
            m = mx;
            #pragma unroll
            for (int h = 0; h < 2; ++h) {
                #pragma unroll
                for (int nf = 0; nf < 4; ++nf)
                    #pragma unroll
                    for (int r = 0; r < 4; ++r) o[h][nf][r] *= corr;
                #pragma unroll
                for (int r = 0; r < 4; ++r) ls[h][r] *= corr;
            }
        }

        bf16x8 vf[4][2];
        #pragma unroll
        for (int nf = 0; nf < 4; ++nf) {
            const u16* Vr = V + (nf * 16 + li) * 64;
            vf[nf][0] = *(const bf16x8*)(Vr + ((lg * 8) ^ rs));
            vf[nf][1] = *(const bf16x8*)(Vr + ((lg * 8 + 32) ^ rs));
        }

        // per-half: P->LDS (swizzled), PV + ones-MFMA row-sum. Shared P buf.
        u16* PW = Pl[wv];
        #pragma unroll
        for (int h = 0; h < 2; ++h) {
            if (h == 0 && !actA) continue;
            const int q0X = (h == 0) ? q0A : q0B;
            const int ntX = (h == 0) ? ntA : ntB;
            const bool maskX = (kt == ntX - 1) && (mode != 1 || h != 1 ? true : false) && (mode != 1);
            // (mode 1 = cat-B never masks; others mask on their last tile)
            #pragma unroll
            for (int r = 0; r < 4; ++r) {
                const int q_ = lg * 4 + r;
                const int qrow = q0X + q_;
                const int qm = q_ & 7;
                #pragma unroll
                for (int kq = 0; kq < 4; ++kq) {
                    float ev = __expf(s[kq][h][r] - m);
                    if (maskX && (koff + kb + kq * 16 + li > qrow)) ev = 0.f;
                    PW[q_ * 64 + ((((2 * kq + (li >> 3)) ^ qm) << 3) | (li & 7))] = f2bf(ev);
                }
            }
            asm volatile("s_waitcnt lgkmcnt(0)" ::: "memory");
            const bf16x8 pa0 = *(const bf16x8*)(PW + li * 64 + ((lg ^ (li & 7)) << 3));
            const bf16x8 pa1 = *(const bf16x8*)(PW + li * 64 + (((lg + 4) ^ (li & 7)) << 3));
            __builtin_amdgcn_s_setprio(1);
            #pragma unroll
            for (int nf = 0; nf < 4; ++nf) {
                f32x4 t = __builtin_amdgcn_mfma_f32_16x16x32_bf16(pa0, vf[nf][0], o[h][nf], 0, 0, 0);
                o[h][nf] = __builtin_amdgcn_mfma_f32_16x16x32_bf16(pa1, vf[nf][1], t, 0, 0, 0);
            }
            ls[h] = __builtin_amdgcn_mfma_f32_16x16x32_bf16(pa0, ones, ls[h], 0, 0, 0);
            ls[h] = __builtin_amdgcn_mfma_f32_16x16x32_bf16(pa1, ones, ls[h], 0, 0, 0);
            __builtin_amdgcn_s_setprio(0);
            asm volatile("s_waitcnt lgkmcnt(0)" ::: "memory");  // reads done before overwrite
        }

        __syncthreads();
        buf ^= 1;
    }

    if (mode == 0) {
        #pragma unroll
        for (int nf = 0; nf < 4; ++nf)
            #pragma unroll
            for (int r = 0; r < 4; ++r) {
                qp[(size_t)(q0A + lg * 4 + r) * NHD + nf * 16 + li] = f2bf(o[0][nf][r] / ls[0][r]);
                qp[(size_t)(q0B + lg * 4 + r) * NHD + nf * 16 + li] = f2bf(o[1][nf][r] / ls[1][r]);
            }
    } else {
        u16* oP = (mode == 1) ? o1 : o2;
        float2* mlP = (mode == 1) ? ml1 : ml2;
        const size_t rbase = (size_t)bh * 1024;
        if (mode == 2) {
            const int lrA = q0A - 1024 + lg * 4;
            #pragma unroll
            for (int nf = 0; nf < 4; ++nf)
                #pragma unroll
                for (int r = 0; r < 4; ++r)
                    oP[(rbase + lrA + r) * 64 + nf * 16 + li] = f2bf(o[0][nf][r]);
            if (li == 0)
                #pragma unroll
                for (int r = 0; r < 4; ++r)
                    ml2[rbase + lrA + r] = make_float2(m, ls[0][r]);
        }
        const int lrB = q0B - 1024 + lg * 4;
        #pragma unroll
        for (int nf = 0; nf < 4; ++nf)
            #pragma unroll
            for (int r = 0; r < 4; ++r)
                oP[(rbase + lrB + r) * 64 + nf * 16 + li] = f2bf(o[1][nf][r]);
        if (li == 0)
            #pragma unroll
            for (int r = 0; r < 4; ++r)
                mlP[rbase + lrB + r] = make_float2(m, ls[1][r]);
    }
    #undef STAGE
}

// ---------------------------------------------------------------------------
// Kernel 2b: merge the two partials for upper rows (s >= 1024) into q_ws.
// ---------------------------------------------------------------------------
__global__ __launch_bounds__(256) void attn_merge(
    const u16* __restrict__ o1, const u16* __restrict__ o2,
    const float2* __restrict__ ml1, const float2* __restrict__ ml2,
    u16* __restrict__ q_ws)
{
    const int t = blockIdx.x * 256 + threadIdx.x;   // 262144 threads
    const int row = t >> 3;                          // bh*1024 + lr
    const int dd = (t & 7) * 8;
    const int bh = row >> 10, lr = row & 1023;
    const float2 a = ml1[row], b = ml2[row];
    const float mm = fmaxf(a.x, b.x);
    const float w1 = __expf(a.x - mm), w2 = __expf(b.x - mm);
    const float den = w1 * a.y + w2 * b.y;
    const float s1 = w1 / den, s2 = w2 / den;
    const bf16x8 v1 = *(const bf16x8*)(o1 + (size_t)row * 64 + dd);
    const bf16x8 v2 = *(const bf16x8*)(o2 + (size_t)row * 64 + dd);
    bf16x8 r;
    #pragma unroll
    for (int j = 0; j < 8; ++j)
        r[j] = (short)f2bf(bf2f((u16)v1[j]) * s1 + bf2f((u16)v2[j]) * s2);
    *(bf16x8*)(q_ws + (size_t)bh * NS * NHD + (size_t)(1024 + lr) * NHD + dd) = r;
}

// ---------------------------------------------------------------------------
// Kernel 3: output projection, 128x128 / BK=64. A = attn output in q_ws
// ([B,H,S,HD] permuted; each BK slice is one head's contiguous 64).
// ---------------------------------------------------------------------------
template<bool BF>
__global__ __launch_bounds__(256) void out_gemm(
    const u16* __restrict__ Aq,
    const float* __restrict__ Wf, const u16* __restrict__ WbT,
    const float* __restrict__ bias, float* __restrict__ outp)
{
    __shared__ __align__(16) u16 As[128 * 64];
    __shared__ __align__(16) u16 Bs[128 * 64];

    const int bm = blockIdx.x & 31;
    const int bn = blockIdx.x >> 5;        // 8 N-tiles
    const int m0 = bm * 128, n0 = bn * 128;
    const int tid = threadIdx.x;
    const int lane = tid & 63, wv = tid >> 6;
    const int wm = wv >> 1, wn = wv & 1;
    const int li = lane & 15, lg = lane >> 4;

    f32x4 acc[4][4];
    #pragma unroll
    for (int i = 0; i < 4; ++i)
        #pragma unroll
        for (int j = 0; j < 4; ++j)
            acc[i][j] = (f32x4){0.f, 0.f, 0.f, 0.f};

    for (int k0 = 0; k0 < ND; k0 += 64) {
        const int h = k0 >> 6;
        #pragma unroll
        for (int i = 0; i < 4; ++i) {
            const int r0 = (i * 4 + wv) * 8;
            const int gm = m0 + r0 + (lane >> 3);
            const int b_ = gm >> 11, sI = gm & 2047;
            gload_lds16(Aq + (((size_t)(b_ * NH + h)) * NS + sI) * NHD + (lane & 7) * 8,
                        &As[r0 * 64]);
            if constexpr (BF)
                gload_lds16(WbT + (size_t)(n0 + r0 + (lane >> 3)) * ND + k0 + (lane & 7) * 8,
                            &Bs[r0 * 64]);
        }
        if constexpr (!BF) {
            #pragma unroll
            for (int i = 0; i < 4; ++i) {
                const int krow = 16 * i + (tid >> 4), ncol = (tid & 15) * 8;
                bf16x8 bv = load8f(Wf + (size_t)(k0 + krow) * ND + n0 + ncol);
                #pragma unroll
                for (int jj = 0; jj < 8; ++jj)
                    Bs[(ncol + jj) * 64 + krow] = (u16)bv[jj];
            }
        }
        __syncthreads();

        bf16x8 a[4][2], b[4][2];
        #pragma unroll
        for (int i = 0; i < 4; ++i)
            #pragma unroll
            for (int kk = 0; kk < 2; ++kk)
                a[i][kk] = *(const bf16x8*)(&As[(wm * 64 + i * 16 + li) * 64 + kk * 32 + lg * 8]);
        #pragma unroll
        for (int j = 0; j < 4; ++j)
            #pragma unroll
            for (int kk = 0; kk < 2; ++kk)
                b[j][kk] = *(const bf16x8*)(&Bs[(wn * 64 + j * 16 + li) * 64 + kk * 32 + lg * 8]);
        #pragma unroll
        for (int i = 0; i < 4; ++i)
            #pragma unroll
            for (int j = 0; j < 4; ++j) {
                acc[i][j] = __builtin_amdgcn_mfma_f32_16x16x32_bf16(a[i][0], b[j][0], acc[i][j], 0, 0, 0);
                acc[i][j] = __builtin_amdgcn_mfma_f32_16x16x32_bf16(a[i][1], b[j][1], acc[i][j], 0, 0, 0);
            }
        __syncthreads();
    }

    #pragma unroll
    for (int i = 0; i < 4; ++i) {
      #pragma unroll
      for (int j = 0; j < 4; ++j) {
        const int gn = n0 + wn * 64 + j * 16 + li;
        const float bval = bias[gn];
        #pragma unroll
        for (int r = 0; r < 4; ++r) {
            const int gm = m0 + wm * 64 + i * 16 + lg * 4 + r;
            outp[(size_t)gm * ND + gn] = acc[i][j][r] + bval;
        }
      }
    }
}

// ---------------------------------------------------------------------------
extern "C" void kernel_launch(void* const* d_in, const int* in_sizes, int n_in,
                              void* d_out, int out_size, void* d_ws, size_t ws_size,
                              hipStream_t stream)
{
    const float* X    = (const float*)d_in[0];
    // d_in[1] = causal mask (bool) — deterministic triu(k=1), not read
    const float* Wqkv = (const float*)d_in[2];
    const float* bqkv = (const float*)d_in[3];
    const float* Wout = (const float*)d_in[4];
    const float* bout = (const float*)d_in[5];

    const size_t HE = (size_t)NB * NH * NS * NHD;   // 4,194,304

    float* out  = (float*)d_out;
    float* kout = out + HE;
    float* vout = kout + HE;

    u16* q_ws  = (u16*)d_ws;        // 8 MB: Q bf16 (pre-scaled) -> attn out
    u16* vT_ws = q_ws + HE;         // 8 MB: V^T bf16 [B,H,HD,S]
    u16* k_ws  = vT_ws + HE;        // 8 MB: K bf16 [B,H,S,HD]

    u16* Xb     = k_ws + HE;                    // 8 MB (dead after qkv)
    u16* WqkvT  = Xb + (size_t)NM * ND;         // 6 MB (dead after qkv)
    u16* WoutT  = WqkvT + (size_t)ND * N3;      // 2 MB (live until out_gemm)
    const bool big = ws_size >= (size_t)41943040;   // 40 MB

    // attention partials (upper rows): 4 MB + 4 MB + 256 KB + 256 KB
    const size_t UPR = (size_t)NB * NH * 1024;      // 32768 rows
    u16* o1; u16* o2; float2* ml1; float2* ml2;
    if (big) {
        o1  = Xb;                       // overlays dead Xb
        o2  = Xb + UPR * 64;
        ml1 = (float2*)WqkvT;           // overlays dead WqkvT
        ml2 = ml1 + UPR;
    } else {
        o1  = k_ws + HE;
        o2  = o1 + UPR * 64;
        ml1 = (float2*)(o2 + UPR * 64);
        ml2 = ml1 + UPR;
    }

    if (big) {
        prep_cvt<<<dim3(6144), dim3(256), 0, stream>>>(X, Xb, Wqkv, WqkvT, Wout, WoutT);
        qkv_gemm<true><<<dim3(32 * 24), dim3(256), 0, stream>>>(
            X, Xb, Wqkv, WqkvT, bqkv, q_ws, vT_ws, k_ws, kout, vout);
    } else {
        qkv_gemm<false><<<dim3(32 * 24), dim3(256), 0, stream>>>(
            X, Xb, Wqkv, WqkvT, bqkv, q_ws, vT_ws, k_ws, kout, vout);
    }

    attn_fwd<<<dim3(1024), dim3(256), 0, stream>>>(q_ws, k_ws, vT_ws, o1, o2, ml1, ml2);
    attn_merge<<<dim3(1024), dim3(256), 0, stream>>>(o1, o2, ml1, ml2, q_ws);

    if (big) {
        out_gemm<true><<<dim3(32 * 8), dim3(256), 0, stream>>>(
            q_ws, Wout, WoutT, bout, out);
    } else {
        out_gemm<false><<<dim3(32 * 8), dim3(256), 0, stream>>>(
            q_ws, Wout, WoutT, bout, out);
    }
}

// Round 8
// 134.273 us; speedup vs baseline: 1.8399x; 1.8399x over previous
//
#include <hip/hip_runtime.h>
#include <hip/hip_bf16.h>

typedef short bf16x8 __attribute__((ext_vector_type(8)));
typedef short u16x4v __attribute__((ext_vector_type(4)));
typedef float f32x4  __attribute__((ext_vector_type(4)));
typedef unsigned short u16;
typedef unsigned int   u32;

#define NB   2
#define NS   2048
#define ND   1024
#define NH   16
#define NHD  64
#define N3   3072
#define NM   4096   /* B*S */

__device__ __forceinline__ u16 f2bf(float f) {
    u32 u;
    __builtin_memcpy(&u, &f, 4);
    u += 0x7fffu + ((u >> 16) & 1u);
    return (u16)(u >> 16);
}
// Load 8 consecutive f32, convert RTNE to a bf16x8 fragment.
__device__ __forceinline__ bf16x8 load8f(const float* f) {
    float4 a = *(const float4*)f;
    float4 b = *(const float4*)(f + 4);
    bf16x8 r;
    r[0] = (short)f2bf(a.x); r[1] = (short)f2bf(a.y);
    r[2] = (short)f2bf(a.z); r[3] = (short)f2bf(a.w);
    r[4] = (short)f2bf(b.x); r[5] = (short)f2bf(b.y);
    r[6] = (short)f2bf(b.z); r[7] = (short)f2bf(b.w);
    return r;
}
// Async global->LDS, 16B per lane. LDS dest = wave-uniform base + lane*16.
__device__ __forceinline__ void gload_lds16(const void* g, void* l) {
    __builtin_amdgcn_global_load_lds(
        (const __attribute__((address_space(1))) u32*)g,
        (__attribute__((address_space(3))) u32*)l, 16, 0, 0);
}

// ---------------------------------------------------------------------------
// Kernel 0: prep — X f32->bf16 (blocks [0,2048)), Wqkv transpose+cvt
// ([2048,5120)), Wout transpose+cvt ([5120,6144)).
// ---------------------------------------------------------------------------
__global__ __launch_bounds__(256) void prep_cvt(
    const float* __restrict__ X, u16* __restrict__ Xb,
    const float* __restrict__ Wqkv, u16* __restrict__ WqkvT,
    const float* __restrict__ Wout, u16* __restrict__ WoutT)
{
    __shared__ float t[32][33];
    const int b = blockIdx.x;
    if (b < 2048) {
        const int i = (b * 256 + threadIdx.x) * 8;
        *(bf16x8*)(Xb + i) = load8f(X + i);
        return;
    }
    const float* in; u16* outp; int R, C, tIdx;
    if (b < 5120) { in = Wqkv; outp = WqkvT; R = ND; C = N3; tIdx = b - 2048; }
    else          { in = Wout; outp = WoutT; R = ND; C = ND; tIdx = b - 5120; }
    const int nbc = C >> 5;
    const int r0 = (tIdx / nbc) << 5;
    const int c0 = (tIdx % nbc) << 5;
    const int tr = threadIdx.x >> 3, tc = (threadIdx.x & 7) << 2;
    const float4 v = *(const float4*)(in + (size_t)(r0 + tr) * C + c0 + tc);
    t[tr][tc] = v.x; t[tr][tc + 1] = v.y; t[tr][tc + 2] = v.z; t[tr][tc + 3] = v.w;
    __syncthreads();
    u16x4v ov;
    ov[0] = (short)f2bf(t[tc + 0][tr]); ov[1] = (short)f2bf(t[tc + 1][tr]);
    ov[2] = (short)f2bf(t[tc + 2][tr]); ov[3] = (short)f2bf(t[tc + 3][tr]);
    *(u16x4v*)(outp + (size_t)(c0 + tr) * R + r0 + tc) = ov;
}

// ---------------------------------------------------------------------------
// Kernel 1: QKV projection, 128x128 tile / BK=64. V-class blocks route the
// vT_ws store through a 32KB LDS transpose (coalesced 128B global writes).
// ---------------------------------------------------------------------------
template<bool BF>
__global__ __launch_bounds__(256) void qkv_gemm(
    const float* __restrict__ Xf, const u16* __restrict__ Xb,
    const float* __restrict__ Wf, const u16* __restrict__ WbT,
    const float* __restrict__ bias,
    u16* __restrict__ q_ws, u16* __restrict__ vT_ws, u16* __restrict__ k_ws,
    float* __restrict__ k_out, float* __restrict__ v_out)
{
    __shared__ __align__(16) u16 SM[128 * 128];   // staging (As|Bs) / transpose
    u16* As = SM;                                 // 128x64
    u16* Bs = SM + 8192;                          // 128x64

    const int bm = blockIdx.x & 31;        // 32 M-tiles
    const int bn = blockIdx.x >> 5;        // 24 N-tiles
    const int m0 = bm * 128, n0 = bn * 128;
    const int tid = threadIdx.x;
    const int lane = tid & 63, wv = tid >> 6;
    const int wm = wv >> 1, wn = wv & 1;
    const int li = lane & 15, lg = lane >> 4;

    f32x4 acc[4][4];
    #pragma unroll
    for (int i = 0; i < 4; ++i)
        #pragma unroll
        for (int j = 0; j < 4; ++j)
            acc[i][j] = (f32x4){0.f, 0.f, 0.f, 0.f};

    for (int k0 = 0; k0 < ND; k0 += 64) {
        if constexpr (BF) {
            #pragma unroll
            for (int i = 0; i < 4; ++i) {
                const int r0 = (i * 4 + wv) * 8;
                gload_lds16(Xb  + (size_t)(m0 + r0 + (lane >> 3)) * ND + k0 + (lane & 7) * 8, &As[r0 * 64]);
                gload_lds16(WbT + (size_t)(n0 + r0 + (lane >> 3)) * ND + k0 + (lane & 7) * 8, &Bs[r0 * 64]);
            }
        } else {
            #pragma unroll
            for (int i = 0; i < 4; ++i) {
                const int row = 32 * i + (tid >> 3), col = (tid & 7) * 8;
                *(bf16x8*)(&As[row * 64 + col]) = load8f(Xf + (size_t)(m0 + row) * ND + k0 + col);
            }
            #pragma unroll
            for (int i = 0; i < 4; ++i) {
                const int krow = 16 * i + (tid >> 4), ncol = (tid & 15) * 8;
                bf16x8 bv = load8f(Wf + (size_t)(k0 + krow) * N3 + n0 + ncol);
                #pragma unroll
                for (int jj = 0; jj < 8; ++jj)
                    Bs[(ncol + jj) * 64 + krow] = (u16)bv[jj];
            }
        }
        __syncthreads();

        bf16x8 a[4][2], b[4][2];
        #pragma unroll
        for (int i = 0; i < 4; ++i)
            #pragma unroll
            for (int kk = 0; kk < 2; ++kk)
                a[i][kk] = *(const bf16x8*)(&As[(wm * 64 + i * 16 + li) * 64 + kk * 32 + lg * 8]);
        #pragma unroll
        for (int j = 0; j < 4; ++j)
            #pragma unroll
            for (int kk = 0; kk < 2; ++kk)
                b[j][kk] = *(const bf16x8*)(&Bs[(wn * 64 + j * 16 + li) * 64 + kk * 32 + lg * 8]);
        #pragma unroll
        for (int i = 0; i < 4; ++i)
            #pragma unroll
            for (int j = 0; j < 4; ++j) {
                acc[i][j] = __builtin_amdgcn_mfma_f32_16x16x32_bf16(a[i][0], b[j][0], acc[i][j], 0, 0, 0);
                acc[i][j] = __builtin_amdgcn_mfma_f32_16x16x32_bf16(a[i][1], b[j][1], acc[i][j], 0, 0, 0);
            }
        __syncthreads();
    }

    const int cls = bn >> 3;   // 0=Q, 1=K, 2=V
    if (cls == 2) {
        // f32 output direct; bf16 into LDS transposed [n][m] (XOR-swizzled m)
        #pragma unroll
        for (int i = 0; i < 4; ++i) {
          #pragma unroll
          for (int j = 0; j < 4; ++j) {
            const int gn = n0 + wn * 64 + j * 16 + li;
            const float bval = bias[gn];
            const int c = gn & 1023, h = c >> 6, d = c & 63;
            const int n_ = wn * 64 + j * 16 + li;
            #pragma unroll
            for (int r = 0; r < 4; ++r) {
                const int gm = m0 + wm * 64 + i * 16 + lg * 4 + r;
                const int b_ = gm >> 11, sI = gm & 2047;
                const float v = acc[i][j][r] + bval;
                v_out[(((size_t)(b_ * NH + h)) * NS + sI) * NHD + d] = v;
                const int m_ = wm * 64 + i * 16 + lg * 4 + r;
                SM[n_ * 128 + (m_ ^ ((n_ & 7) << 3))] = f2bf(v);
            }
          }
        }
        __syncthreads();
        const int nrow = tid >> 1, mh = tid & 1;
        const int cdx = (n0 - 2048) + nrow;           // V col 0..1023
        const int hh = cdx >> 6, d = cdx & 63;
        const int b_ = m0 >> 11;
        const int s0 = (m0 & 2047) + mh * 64;
        u16* dst = vT_ws + (((size_t)(b_ * NH + hh)) * NHD + d) * NS + s0;
        #pragma unroll
        for (int c8 = 0; c8 < 8; ++c8) {
            const int m_ = mh * 64 + c8 * 8;
            *(bf16x8*)(dst + c8 * 8) =
                *(const bf16x8*)(&SM[nrow * 128 + (m_ ^ ((nrow & 7) << 3))]);
        }
    } else {
        #pragma unroll
        for (int i = 0; i < 4; ++i) {
          #pragma unroll
          for (int j = 0; j < 4; ++j) {
            const int gn = n0 + wn * 64 + j * 16 + li;
            const float bval = bias[gn];
            const int c = gn & 1023, h = c >> 6, d = c & 63;
            #pragma unroll
            for (int r = 0; r < 4; ++r) {
                const int gm = m0 + wm * 64 + i * 16 + lg * 4 + r;
                const int b_ = gm >> 11, sI = gm & 2047;
                const float v = acc[i][j][r] + bval;
                const size_t hidx = (((size_t)(b_ * NH + h)) * NS + sI) * NHD + d;
                if (cls == 0) {
                    q_ws[hidx] = f2bf(v * 0.125f);
                } else {
                    k_out[hidx] = v;
                    k_ws[hidx] = f2bf(v);
                }
            }
          }
        }
    }
}

// ---------------------------------------------------------------------------
// Kernel 2: causal flash attention. One 64-row q-tile per block, 1024 blocks,
// KBLK=64 double-buffered LDS K/V^T. Complementary-tile XCD swizzle: per XCD
// j in [0,128), head = j>>5, tile = (j>>5&1) ? 31-(j&31) : (j&31) -> each CU
// gets tiles {c, 31-c, c, 31-c} = 66 tile-units, uniform, 4 heads/XCD kept.
// LDS 40960B -> 4 blocks/CU. Deferred max (exact), ones-MFMA row-sum.
// ---------------------------------------------------------------------------
__global__ __launch_bounds__(256, 4) void attn_fwd(
    u16* __restrict__ q_all, const u16* __restrict__ k_all,
    const u16* __restrict__ vT)
{
    __shared__ __align__(16) u16 Ks[2][64 * 64];
    __shared__ __align__(16) u16 Vs[2][64 * 64];
    __shared__ __align__(16) u16 Pl[4][16 * 64];   // XOR-swizzled

    const int tid = threadIdx.x;
    const int wv = tid >> 6, lane = tid & 63;
    const int li = lane & 15, lg = lane >> 4;
    const int bid = blockIdx.x;                 // 1024
    const int xcd = bid & 7, j = bid >> 3;      // j in 0..127 per XCD
    const int bh  = (xcd << 2) | (j >> 5);      // 4 heads per XCD
    const int jj  = j & 31;
    const int qt  = (j & 32) ? (31 - jj) : jj;  // complementary per CU
    const int q0  = qt * 64 + wv * 16;
    const int ntiles = qt + 1;

    u16* qp = q_all + (size_t)bh * NS * NHD;    // read Q, later write O (alias)
    const u16* kp = k_all + (size_t)bh * NS * NHD;
    const u16* vp = vT + (size_t)bh * NHD * NS;

    const int rl = lane >> 3;
    const int gsw = ((lane & 7) * 16) ^ (rl << 4);  // pre-swizzled byte col
    const int rs = (li & 7) << 3;                   // u16-unit read swizzle

    bf16x8 aq0 = *(const bf16x8*)(qp + (size_t)(q0 + li) * NHD + lg * 8);
    bf16x8 aq1 = *(const bf16x8*)(qp + (size_t)(q0 + li) * NHD + 32 + lg * 8);

    f32x4 o[4], ls;
    ls = (f32x4){0.f, 0.f, 0.f, 0.f};
    #pragma unroll
    for (int nf = 0; nf < 4; ++nf) o[nf] = (f32x4){0.f, 0.f, 0.f, 0.f};
    float m = 4.0f;   // deferred-max baseline; exact (common scale of O and l)

    const short onb = (short)0x3F80;
    const bf16x8 ones = {onb, onb, onb, onb, onb, onb, onb, onb};

    #define STAGE(B, KB) do {                                                           \
        _Pragma("unroll")                                                               \
        for (int i_ = 0; i_ < 2; ++i_) {                                                \
            const int row_ = 16 * wv + 8 * i_;                                          \
            gload_lds16((const char*)(kp + (size_t)((KB) + row_ + rl) * NHD) + gsw,     \
                        &Ks[B][row_ * 64]);                                             \
            gload_lds16((const char*)(vp + (size_t)(row_ + rl) * NS + (KB)) + gsw,      \
                        &Vs[B][row_ * 64]);                                             \
        } } while (0)

    STAGE(0, 0);
    __syncthreads();

    int buf = 0;
    for (int kt = 0; kt < ntiles; ++kt) {
        const int kb = kt * 64;
        if (kt + 1 < ntiles) STAGE(buf ^ 1, kb + 64);

        const u16* K = Ks[buf];
        const u16* V = Vs[buf];

        // QK^T: s[kq] rows q0+lg*4+r, key col kq*16+li
        f32x4 s[4];
        __builtin_amdgcn_s_setprio(1);
        #pragma unroll
        for (int kq = 0; kq < 4; ++kq) {
            const u16* Kr = K + (kq * 16 + li) * 64;
            const bf16x8 b0 = *(const bf16x8*)(Kr + ((lg * 8) ^ rs));
            const bf16x8 b1 = *(const bf16x8*)(Kr + ((lg * 8 + 32) ^ rs));
            f32x4 t = (f32x4){0.f, 0.f, 0.f, 0.f};
            t = __builtin_amdgcn_mfma_f32_16x16x32_bf16(aq0, b0, t, 0, 0, 0);
            s[kq] = __builtin_amdgcn_mfma_f32_16x16x32_bf16(aq1, b1, t, 0, 0, 0);
        }
        __builtin_amdgcn_s_setprio(0);

        // deferred max: per-lane tree + wave vote; reduce only on trigger
        float mx = s[0][0];
        #pragma unroll
        for (int kq = 0; kq < 4; ++kq)
            #pragma unroll
            for (int r = 0; r < 4; ++r)
                mx = fmaxf(mx, s[kq][r]);
        if (__any(mx > m)) {
            #pragma unroll
            for (int dd = 1; dd < 64; dd <<= 1)
                mx = fmaxf(mx, __shfl_xor(mx, dd, 64));
            const float corr = __expf(m - mx);
            m = mx;
            #pragma unroll
            for (int nf = 0; nf < 4; ++nf)
                #pragma unroll
                for (int r = 0; r < 4; ++r) o[nf][r] *= corr;
            #pragma unroll
            for (int r = 0; r < 4; ++r) ls[r] *= corr;
        }

        // V fragments
        bf16x8 vf[4][2];
        #pragma unroll
        for (int nf = 0; nf < 4; ++nf) {
            const u16* Vr = V + (nf * 16 + li) * 64;
            vf[nf][0] = *(const bf16x8*)(Vr + ((lg * 8) ^ rs));
            vf[nf][1] = *(const bf16x8*)(Vr + ((lg * 8 + 32) ^ rs));
        }

        // P = exp(s-m) -> LDS (swizzled); mask on last tile only
        const bool maskt = (kt == ntiles - 1);
        u16* PW = Pl[wv];
        #pragma unroll
        for (int r = 0; r < 4; ++r) {
            const int q_ = lg * 4 + r;
            const int qrow = q0 + q_;
            const int qm = q_ & 7;
            #pragma unroll
            for (int kq = 0; kq < 4; ++kq) {
                float ev = __expf(s[kq][r] - m);
                if (maskt && (kb + kq * 16 + li > qrow)) ev = 0.f;
                PW[q_ * 64 + ((((2 * kq + (li >> 3)) ^ qm) << 3) | (li & 7))] = f2bf(ev);
            }
        }
        asm volatile("s_waitcnt lgkmcnt(0)" ::: "memory");
        const bf16x8 pa0 = *(const bf16x8*)(PW + li * 64 + ((lg ^ (li & 7)) << 3));
        const bf16x8 pa1 = *(const bf16x8*)(PW + li * 64 + (((lg + 4) ^ (li & 7)) << 3));
        __builtin_amdgcn_s_setprio(1);
        #pragma unroll
        for (int nf = 0; nf < 4; ++nf) {
            f32x4 t = __builtin_amdgcn_mfma_f32_16x16x32_bf16(pa0, vf[nf][0], o[nf], 0, 0, 0);
            o[nf] = __builtin_amdgcn_mfma_f32_16x16x32_bf16(pa1, vf[nf][1], t, 0, 0, 0);
        }
        ls = __builtin_amdgcn_mfma_f32_16x16x32_bf16(pa0, ones, ls, 0, 0, 0);
        ls = __builtin_amdgcn_mfma_f32_16x16x32_bf16(pa1, ones, ls, 0, 0, 0);
        __builtin_amdgcn_s_setprio(0);

        __syncthreads();   // prefetch arrived + P/K/V buffer reuse safe
        buf ^= 1;
    }

    #pragma unroll
    for (int nf = 0; nf < 4; ++nf)
        #pragma unroll
        for (int r = 0; r < 4; ++r)
            qp[(size_t)(q0 + lg * 4 + r) * NHD + nf * 16 + li] = f2bf(o[nf][r] / ls[r]);
    #undef STAGE
}

// ---------------------------------------------------------------------------
// Kernel 3: output projection, 128x128 / BK=64. A = attn output in q_ws
// ([B,H,S,HD] permuted; each BK slice is one head's contiguous 64).
// ---------------------------------------------------------------------------
template<bool BF>
__global__ __launch_bounds__(256) void out_gemm(
    const u16* __restrict__ Aq,
    const float* __restrict__ Wf, const u16* __restrict__ WbT,
    const float* __restrict__ bias, float* __restrict__ outp)
{
    __shared__ __align__(16) u16 As[128 * 64];
    __shared__ __align__(16) u16 Bs[128 * 64];

    const int bm = blockIdx.x & 31;
    const int bn = blockIdx.x >> 5;        // 8 N-tiles
    const int m0 = bm * 128, n0 = bn * 128;
    const int tid = threadIdx.x;
    const int lane = tid & 63, wv = tid >> 6;
    const int wm = wv >> 1, wn = wv & 1;
    const int li = lane & 15, lg = lane >> 4;

    f32x4 acc[4][4];
    #pragma unroll
    for (int i = 0; i < 4; ++i)
        #pragma unroll
        for (int j = 0; j < 4; ++j)
            acc[i][j] = (f32x4){0.f, 0.f, 0.f, 0.f};

    for (int k0 = 0; k0 < ND; k0 += 64) {
        const int h = k0 >> 6;
        #pragma unroll
        for (int i = 0; i < 4; ++i) {
            const int r0 = (i * 4 + wv) * 8;
            const int gm = m0 + r0 + (lane >> 3);
            const int b_ = gm >> 11, sI = gm & 2047;
            gload_lds16(Aq + (((size_t)(b_ * NH + h)) * NS + sI) * NHD + (lane & 7) * 8,
                        &As[r0 * 64]);
            if constexpr (BF)
                gload_lds16(WbT + (size_t)(n0 + r0 + (lane >> 3)) * ND + k0 + (lane & 7) * 8,
                            &Bs[r0 * 64]);
        }
        if constexpr (!BF) {
            #pragma unroll
            for (int i = 0; i < 4; ++i) {
                const int krow = 16 * i + (tid >> 4), ncol = (tid & 15) * 8;
                bf16x8 bv = load8f(Wf + (size_t)(k0 + krow) * ND + n0 + ncol);
                #pragma unroll
                for (int jj = 0; jj < 8; ++jj)
                    Bs[(ncol + jj) * 64 + krow] = (u16)bv[jj];
            }
        }
        __syncthreads();

        bf16x8 a[4][2], b[4][2];
        #pragma unroll
        for (int i = 0; i < 4; ++i)
            #pragma unroll
            for (int kk = 0; kk < 2; ++kk)
                a[i][kk] = *(const bf16x8*)(&As[(wm * 64 + i * 16 + li) * 64 + kk * 32 + lg * 8]);
        #pragma unroll
        for (int j = 0; j < 4; ++j)
            #pragma unroll
            for (int kk = 0; kk < 2; ++kk)
                b[j][kk] = *(const bf16x8*)(&Bs[(wn * 64 + j * 16 + li) * 64 + kk * 32 + lg * 8]);
        #pragma unroll
        for (int i = 0; i < 4; ++i)
            #pragma unroll
            for (int j = 0; j < 4; ++j) {
                acc[i][j] = __builtin_amdgcn_mfma_f32_16x16x32_bf16(a[i][0], b[j][0], acc[i][j], 0, 0, 0);
                acc[i][j] = __builtin_amdgcn_mfma_f32_16x16x32_bf16(a[i][1], b[j][1], acc[i][j], 0, 0, 0);
            }
        __syncthreads();
    }

    #pragma unroll
    for (int i = 0; i < 4; ++i) {
      #pragma unroll
      for (int j = 0; j < 4; ++j) {
        const int gn = n0 + wn * 64 + j * 16 + li;
        const float bval = bias[gn];
        #pragma unroll
        for (int r = 0; r < 4; ++r) {
            const int gm = m0 + wm * 64 + i * 16 + lg * 4 + r;
            outp[(size_t)gm * ND + gn] = acc[i][j][r] + bval;
        }
      }
    }
}

// ---------------------------------------------------------------------------
extern "C" void kernel_launch(void* const* d_in, const int* in_sizes, int n_in,
                              void* d_out, int out_size, void* d_ws, size_t ws_size,
                              hipStream_t stream)
{
    const float* X    = (const float*)d_in[0];
    // d_in[1] = causal mask (bool) — deterministic triu(k=1), not read
    const float* Wqkv = (const float*)d_in[2];
    const float* bqkv = (const float*)d_in[3];
    const float* Wout = (const float*)d_in[4];
    const float* bout = (const float*)d_in[5];

    const size_t HE = (size_t)NB * NH * NS * NHD;   // 4,194,304

    float* out  = (float*)d_out;
    float* kout = out + HE;
    float* vout = kout + HE;

    u16* q_ws  = (u16*)d_ws;        // 8 MB: Q bf16 (pre-scaled) -> attn out
    u16* vT_ws = q_ws + HE;         // 8 MB: V^T bf16 [B,H,HD,S]
    u16* k_ws  = vT_ws + HE;        // 8 MB: K bf16 [B,H,S,HD]

    u16* Xb     = k_ws + HE;                    // 8 MB (dead after qkv)
    u16* WqkvT  = Xb + (size_t)NM * ND;         // 6 MB (dead after qkv)
    u16* WoutT  = WqkvT + (size_t)ND * N3;      // 2 MB (live until out_gemm)
    const bool big = ws_size >= (size_t)41943040;   // 40 MB

    if (big) {
        prep_cvt<<<dim3(6144), dim3(256), 0, stream>>>(X, Xb, Wqkv, WqkvT, Wout, WoutT);
        qkv_gemm<true><<<dim3(32 * 24), dim3(256), 0, stream>>>(
            X, Xb, Wqkv, WqkvT, bqkv, q_ws, vT_ws, k_ws, kout, vout);
    } else {
        qkv_gemm<false><<<dim3(32 * 24), dim3(256), 0, stream>>>(
            X, Xb, Wqkv, WqkvT, bqkv, q_ws, vT_ws, k_ws, kout, vout);
    }

    attn_fwd<<<dim3(1024), dim3(256), 0, stream>>>(q_ws, k_ws, vT_ws);

    if (big) {
        out_gemm<true><<<dim3(32 * 8), dim3(256), 0, stream>>>(
            q_ws, Wout, WoutT, bout, out);
    } else {
        out_gemm<false><<<dim3(32 * 8), dim3(256), 0, stream>>>(
            q_ws, Wout, WoutT, bout, out);
    }
}

// Round 9
// 126.012 us; speedup vs baseline: 1.9605x; 1.0656x over previous
//
#include <hip/hip_runtime.h>
#include <hip/hip_bf16.h>

typedef short bf16x8 __attribute__((ext_vector_type(8)));
typedef short u16x4v __attribute__((ext_vector_type(4)));
typedef float f32x4  __attribute__((ext_vector_type(4)));
typedef unsigned short u16;
typedef unsigned int   u32;

#define NB   2
#define NS   2048
#define ND   1024
#define NH   16
#define NHD  64
#define N3   3072
#define NM   4096   /* B*S */

__device__ __forceinline__ u16 f2bf(float f) {
    u32 u;
    __builtin_memcpy(&u, &f, 4);
    u += 0x7fffu + ((u >> 16) & 1u);
    return (u16)(u >> 16);
}
// Load 8 consecutive f32, convert RTNE to a bf16x8 fragment.
__device__ __forceinline__ bf16x8 load8f(const float* f) {
    float4 a = *(const float4*)f;
    float4 b = *(const float4*)(f + 4);
    bf16x8 r;
    r[0] = (short)f2bf(a.x); r[1] = (short)f2bf(a.y);
    r[2] = (short)f2bf(a.z); r[3] = (short)f2bf(a.w);
    r[4] = (short)f2bf(b.x); r[5] = (short)f2bf(b.y);
    r[6] = (short)f2bf(b.z); r[7] = (short)f2bf(b.w);
    return r;
}
// Async global->LDS, 16B per lane. LDS dest = wave-uniform base + lane*16.
__device__ __forceinline__ void gload_lds16(const void* g, void* l) {
    __builtin_amdgcn_global_load_lds(
        (const __attribute__((address_space(1))) u32*)g,
        (__attribute__((address_space(3))) u32*)l, 16, 0, 0);
}

// ---------------------------------------------------------------------------
// Kernel 0: prep — X f32->bf16 (blocks [0,2048)), Wqkv transpose+cvt
// ([2048,5120)), Wout transpose+cvt ([5120,6144)).
// ---------------------------------------------------------------------------
__global__ __launch_bounds__(256) void prep_cvt(
    const float* __restrict__ X, u16* __restrict__ Xb,
    const float* __restrict__ Wqkv, u16* __restrict__ WqkvT,
    const float* __restrict__ Wout, u16* __restrict__ WoutT)
{
    __shared__ float t[32][33];
    const int b = blockIdx.x;
    if (b < 2048) {
        const int i = (b * 256 + threadIdx.x) * 8;
        *(bf16x8*)(Xb + i) = load8f(X + i);
        return;
    }
    const float* in; u16* outp; int R, C, tIdx;
    if (b < 5120) { in = Wqkv; outp = WqkvT; R = ND; C = N3; tIdx = b - 2048; }
    else          { in = Wout; outp = WoutT; R = ND; C = ND; tIdx = b - 5120; }
    const int nbc = C >> 5;
    const int r0 = (tIdx / nbc) << 5;
    const int c0 = (tIdx % nbc) << 5;
    const int tr = threadIdx.x >> 3, tc = (threadIdx.x & 7) << 2;
    const float4 v = *(const float4*)(in + (size_t)(r0 + tr) * C + c0 + tc);
    t[tr][tc] = v.x; t[tr][tc + 1] = v.y; t[tr][tc + 2] = v.z; t[tr][tc + 3] = v.w;
    __syncthreads();
    u16x4v ov;
    ov[0] = (short)f2bf(t[tc + 0][tr]); ov[1] = (short)f2bf(t[tc + 1][tr]);
    ov[2] = (short)f2bf(t[tc + 2][tr]); ov[3] = (short)f2bf(t[tc + 3][tr]);
    *(u16x4v*)(outp + (size_t)(c0 + tr) * R + r0 + tc) = ov;
}

// ---------------------------------------------------------------------------
// Kernel 1: QKV projection, 128x128 tile / BK=64, XOR-swizzled LDS
// (staging via pre-swizzled global source; reads XOR (li&7)<<3 u16 units).
// V-class blocks route vT_ws through a 32KB LDS transpose.
// ---------------------------------------------------------------------------
template<bool BF>
__global__ __launch_bounds__(256) void qkv_gemm(
    const float* __restrict__ Xf, const u16* __restrict__ Xb,
    const float* __restrict__ Wf, const u16* __restrict__ WbT,
    const float* __restrict__ bias,
    u16* __restrict__ q_ws, u16* __restrict__ vT_ws, u16* __restrict__ k_ws,
    float* __restrict__ k_out, float* __restrict__ v_out)
{
    __shared__ __align__(16) u16 SM[128 * 128];   // staging (As|Bs) / transpose
    u16* As = SM;                                 // 128x64 (swizzled)
    u16* Bs = SM + 8192;                          // 128x64 (swizzled)

    const int bm = blockIdx.x & 31;        // 32 M-tiles
    const int bn = blockIdx.x >> 5;        // 24 N-tiles
    const int m0 = bm * 128, n0 = bn * 128;
    const int tid = threadIdx.x;
    const int lane = tid & 63, wv = tid >> 6;
    const int wm = wv >> 1, wn = wv & 1;
    const int li = lane & 15, lg = lane >> 4;
    const int gsw = ((lane & 7) * 16) ^ ((lane >> 3) << 4);  // staging byte col
    const int rsw = (li & 7) << 3;                           // read swz (u16)

    f32x4 acc[4][4];
    #pragma unroll
    for (int i = 0; i < 4; ++i)
        #pragma unroll
        for (int j = 0; j < 4; ++j)
            acc[i][j] = (f32x4){0.f, 0.f, 0.f, 0.f};

    for (int k0 = 0; k0 < ND; k0 += 64) {
        if constexpr (BF) {
            #pragma unroll
            for (int i = 0; i < 4; ++i) {
                const int r0 = (i * 4 + wv) * 8;
                gload_lds16((const char*)(Xb  + (size_t)(m0 + r0 + (lane >> 3)) * ND + k0) + gsw, &As[r0 * 64]);
                gload_lds16((const char*)(WbT + (size_t)(n0 + r0 + (lane >> 3)) * ND + k0) + gsw, &Bs[r0 * 64]);
            }
        } else {
            #pragma unroll
            for (int i = 0; i < 4; ++i) {
                const int row = 32 * i + (tid >> 3), col = (tid & 7) * 8;
                *(bf16x8*)(&As[row * 64 + (col ^ ((row & 7) * 8))]) =
                    load8f(Xf + (size_t)(m0 + row) * ND + k0 + col);
            }
            #pragma unroll
            for (int i = 0; i < 4; ++i) {
                const int krow = 16 * i + (tid >> 4), ncol = (tid & 15) * 8;
                bf16x8 bv = load8f(Wf + (size_t)(k0 + krow) * N3 + n0 + ncol);
                #pragma unroll
                for (int jj = 0; jj < 8; ++jj) {
                    const int n_ = ncol + jj;
                    Bs[n_ * 64 + ((((krow >> 3) ^ (n_ & 7)) << 3) | (krow & 7))] = (u16)bv[jj];
                }
            }
        }
        __syncthreads();

        bf16x8 a[4][2], b[4][2];
        #pragma unroll
        for (int i = 0; i < 4; ++i)
            #pragma unroll
            for (int kk = 0; kk < 2; ++kk)
                a[i][kk] = *(const bf16x8*)(&As[(wm * 64 + i * 16 + li) * 64 + ((kk * 32 + lg * 8) ^ rsw)]);
        #pragma unroll
        for (int j = 0; j < 4; ++j)
            #pragma unroll
            for (int kk = 0; kk < 2; ++kk)
                b[j][kk] = *(const bf16x8*)(&Bs[(wn * 64 + j * 16 + li) * 64 + ((kk * 32 + lg * 8) ^ rsw)]);
        #pragma unroll
        for (int i = 0; i < 4; ++i)
            #pragma unroll
            for (int j = 0; j < 4; ++j) {
                acc[i][j] = __builtin_amdgcn_mfma_f32_16x16x32_bf16(a[i][0], b[j][0], acc[i][j], 0, 0, 0);
                acc[i][j] = __builtin_amdgcn_mfma_f32_16x16x32_bf16(a[i][1], b[j][1], acc[i][j], 0, 0, 0);
            }
        __syncthreads();
    }

    const int cls = bn >> 3;   // 0=Q, 1=K, 2=V
    if (cls == 2) {
        // f32 output direct; bf16 into LDS transposed [n][m] (XOR-swizzled m)
        #pragma unroll
        for (int i = 0; i < 4; ++i) {
          #pragma unroll
          for (int j = 0; j < 4; ++j) {
            const int gn = n0 + wn * 64 + j * 16 + li;
            const float bval = bias[gn];
            const int c = gn & 1023, h = c >> 6, d = c & 63;
            const int n_ = wn * 64 + j * 16 + li;
            #pragma unroll
            for (int r = 0; r < 4; ++r) {
                const int gm = m0 + wm * 64 + i * 16 + lg * 4 + r;
                const int b_ = gm >> 11, sI = gm & 2047;
                const float v = acc[i][j][r] + bval;
                v_out[(((size_t)(b_ * NH + h)) * NS + sI) * NHD + d] = v;
                const int m_ = wm * 64 + i * 16 + lg * 4 + r;
                SM[n_ * 128 + (m_ ^ ((n_ & 7) << 3))] = f2bf(v);
            }
          }
        }
        __syncthreads();
        const int nrow = tid >> 1, mh = tid & 1;
        const int cdx = (n0 - 2048) + nrow;           // V col 0..1023
        const int hh = cdx >> 6, d = cdx & 63;
        const int b_ = m0 >> 11;
        const int s0 = (m0 & 2047) + mh * 64;
        u16* dst = vT_ws + (((size_t)(b_ * NH + hh)) * NHD + d) * NS + s0;
        #pragma unroll
        for (int c8 = 0; c8 < 8; ++c8) {
            const int m_ = mh * 64 + c8 * 8;
            *(bf16x8*)(dst + c8 * 8) =
                *(const bf16x8*)(&SM[nrow * 128 + (m_ ^ ((nrow & 7) << 3))]);
        }
    } else {
        #pragma unroll
        for (int i = 0; i < 4; ++i) {
          #pragma unroll
          for (int j = 0; j < 4; ++j) {
            const int gn = n0 + wn * 64 + j * 16 + li;
            const float bval = bias[gn];
            const int c = gn & 1023, h = c >> 6, d = c & 63;
            #pragma unroll
            for (int r = 0; r < 4; ++r) {
                const int gm = m0 + wm * 64 + i * 16 + lg * 4 + r;
                const int b_ = gm >> 11, sI = gm & 2047;
                const float v = acc[i][j][r] + bval;
                const size_t hidx = (((size_t)(b_ * NH + h)) * NS + sI) * NHD + d;
                if (cls == 0) {
                    q_ws[hidx] = f2bf(v * 0.125f);
                } else {
                    k_out[hidx] = v;
                    k_ws[hidx] = f2bf(v);
                }
            }
          }
        }
    }
}

// ---------------------------------------------------------------------------
// Kernel 2: causal flash attention. One 64-row q-tile per block, 1024 blocks,
// KBLK=64 double-buffered LDS K/V^T. Complementary-tile XCD swizzle: per XCD
// j in [0,128), head = j>>5, tile = (j>>5&1) ? 31-(j&31) : (j&31) -> each CU
// gets tiles {c, 31-c, c, 31-c} = 66 tile-units, uniform, 4 heads/XCD kept.
// LDS 40960B -> 4 blocks/CU. Deferred max (exact), ones-MFMA row-sum.
// ---------------------------------------------------------------------------
__global__ __launch_bounds__(256, 4) void attn_fwd(
    u16* __restrict__ q_all, const u16* __restrict__ k_all,
    const u16* __restrict__ vT)
{
    __shared__ __align__(16) u16 Ks[2][64 * 64];
    __shared__ __align__(16) u16 Vs[2][64 * 64];
    __shared__ __align__(16) u16 Pl[4][16 * 64];   // XOR-swizzled

    const int tid = threadIdx.x;
    const int wv = tid >> 6, lane = tid & 63;
    const int li = lane & 15, lg = lane >> 4;
    const int bid = blockIdx.x;                 // 1024
    const int xcd = bid & 7, j = bid >> 3;      // j in 0..127 per XCD
    const int bh  = (xcd << 2) | (j >> 5);      // 4 heads per XCD
    const int jj  = j & 31;
    const int qt  = (j & 32) ? (31 - jj) : jj;  // complementary per CU
    const int q0  = qt * 64 + wv * 16;
    const int ntiles = qt + 1;

    u16* qp = q_all + (size_t)bh * NS * NHD;    // read Q, later write O (alias)
    const u16* kp = k_all + (size_t)bh * NS * NHD;
    const u16* vp = vT + (size_t)bh * NHD * NS;

    const int rl = lane >> 3;
    const int gsw = ((lane & 7) * 16) ^ (rl << 4);  // pre-swizzled byte col
    const int rs = (li & 7) << 3;                   // u16-unit read swizzle

    bf16x8 aq0 = *(const bf16x8*)(qp + (size_t)(q0 + li) * NHD + lg * 8);
    bf16x8 aq1 = *(const bf16x8*)(qp + (size_t)(q0 + li) * NHD + 32 + lg * 8);

    f32x4 o[4], ls;
    ls = (f32x4){0.f, 0.f, 0.f, 0.f};
    #pragma unroll
    for (int nf = 0; nf < 4; ++nf) o[nf] = (f32x4){0.f, 0.f, 0.f, 0.f};
    float m = 4.0f;   // deferred-max baseline; exact (common scale of O and l)

    const short onb = (short)0x3F80;
    const bf16x8 ones = {onb, onb, onb, onb, onb, onb, onb, onb};

    #define STAGE(B, KB) do {                                                           \
        _Pragma("unroll")                                                               \
        for (int i_ = 0; i_ < 2; ++i_) {                                                \
            const int row_ = 16 * wv + 8 * i_;                                          \
            gload_lds16((const char*)(kp + (size_t)((KB) + row_ + rl) * NHD) + gsw,     \
                        &Ks[B][row_ * 64]);                                             \
            gload_lds16((const char*)(vp + (size_t)(row_ + rl) * NS + (KB)) + gsw,      \
                        &Vs[B][row_ * 64]);                                             \
        } } while (0)

    STAGE(0, 0);
    __syncthreads();

    int buf = 0;
    for (int kt = 0; kt < ntiles; ++kt) {
        const int kb = kt * 64;
        if (kt + 1 < ntiles) STAGE(buf ^ 1, kb + 64);

        const u16* K = Ks[buf];
        const u16* V = Vs[buf];

        // QK^T: s[kq] rows q0+lg*4+r, key col kq*16+li
        f32x4 s[4];
        __builtin_amdgcn_s_setprio(1);
        #pragma unroll
        for (int kq = 0; kq < 4; ++kq) {
            const u16* Kr = K + (kq * 16 + li) * 64;
            const bf16x8 b0 = *(const bf16x8*)(Kr + ((lg * 8) ^ rs));
            const bf16x8 b1 = *(const bf16x8*)(Kr + ((lg * 8 + 32) ^ rs));
            f32x4 t = (f32x4){0.f, 0.f, 0.f, 0.f};
            t = __builtin_amdgcn_mfma_f32_16x16x32_bf16(aq0, b0, t, 0, 0, 0);
            s[kq] = __builtin_amdgcn_mfma_f32_16x16x32_bf16(aq1, b1, t, 0, 0, 0);
        }
        __builtin_amdgcn_s_setprio(0);

        // deferred max: per-lane tree + wave vote; reduce only on trigger
        float mx = s[0][0];
        #pragma unroll
        for (int kq = 0; kq < 4; ++kq)
            #pragma unroll
            for (int r = 0; r < 4; ++r)
                mx = fmaxf(mx, s[kq][r]);
        if (__any(mx > m)) {
            #pragma unroll
            for (int dd = 1; dd < 64; dd <<= 1)
                mx = fmaxf(mx, __shfl_xor(mx, dd, 64));
            const float corr = __expf(m - mx);
            m = mx;
            #pragma unroll
            for (int nf = 0; nf < 4; ++nf)
                #pragma unroll
                for (int r = 0; r < 4; ++r) o[nf][r] *= corr;
            #pragma unroll
            for (int r = 0; r < 4; ++r) ls[r] *= corr;
        }

        // V fragments
        bf16x8 vf[4][2];
        #pragma unroll
        for (int nf = 0; nf < 4; ++nf) {
            const u16* Vr = V + (nf * 16 + li) * 64;
            vf[nf][0] = *(const bf16x8*)(Vr + ((lg * 8) ^ rs));
            vf[nf][1] = *(const bf16x8*)(Vr + ((lg * 8 + 32) ^ rs));
        }

        // P = exp(s-m) -> LDS (swizzled); mask on last tile only
        const bool maskt = (kt == ntiles - 1);
        u16* PW = Pl[wv];
        #pragma unroll
        for (int r = 0; r < 4; ++r) {
            const int q_ = lg * 4 + r;
            const int qrow = q0 + q_;
            const int qm = q_ & 7;
            #pragma unroll
            for (int kq = 0; kq < 4; ++kq) {
                float ev = __expf(s[kq][r] - m);
                if (maskt && (kb + kq * 16 + li > qrow)) ev = 0.f;
                PW[q_ * 64 + ((((2 * kq + (li >> 3)) ^ qm) << 3) | (li & 7))] = f2bf(ev);
            }
        }
        asm volatile("s_waitcnt lgkmcnt(0)" ::: "memory");
        const bf16x8 pa0 = *(const bf16x8*)(PW + li * 64 + ((lg ^ (li & 7)) << 3));
        const bf16x8 pa1 = *(const bf16x8*)(PW + li * 64 + (((lg + 4) ^ (li & 7)) << 3));
        __builtin_amdgcn_s_setprio(1);
        #pragma unroll
        for (int nf = 0; nf < 4; ++nf) {
            f32x4 t = __builtin_amdgcn_mfma_f32_16x16x32_bf16(pa0, vf[nf][0], o[nf], 0, 0, 0);
            o[nf] = __builtin_amdgcn_mfma_f32_16x16x32_bf16(pa1, vf[nf][1], t, 0, 0, 0);
        }
        ls = __builtin_amdgcn_mfma_f32_16x16x32_bf16(pa0, ones, ls, 0, 0, 0);
        ls = __builtin_amdgcn_mfma_f32_16x16x32_bf16(pa1, ones, ls, 0, 0, 0);
        __builtin_amdgcn_s_setprio(0);

        __syncthreads();   // prefetch arrived + P/K/V buffer reuse safe
        buf ^= 1;
    }

    #pragma unroll
    for (int nf = 0; nf < 4; ++nf)
        #pragma unroll
        for (int r = 0; r < 4; ++r)
            qp[(size_t)(q0 + lg * 4 + r) * NHD + nf * 16 + li] = f2bf(o[nf][r] / ls[r]);
    #undef STAGE
}

// ---------------------------------------------------------------------------
// Kernel 3: output projection, 128x128 / BK=64, XOR-swizzled LDS.
// A = attn output in q_ws ([B,H,S,HD] permuted).
// ---------------------------------------------------------------------------
template<bool BF>
__global__ __launch_bounds__(256) void out_gemm(
    const u16* __restrict__ Aq,
    const float* __restrict__ Wf, const u16* __restrict__ WbT,
    const float* __restrict__ bias, float* __restrict__ outp)
{
    __shared__ __align__(16) u16 As[128 * 64];
    __shared__ __align__(16) u16 Bs[128 * 64];

    const int bm = blockIdx.x & 31;
    const int bn = blockIdx.x >> 5;        // 8 N-tiles
    const int m0 = bm * 128, n0 = bn * 128;
    const int tid = threadIdx.x;
    const int lane = tid & 63, wv = tid >> 6;
    const int wm = wv >> 1, wn = wv & 1;
    const int li = lane & 15, lg = lane >> 4;
    const int gsw = ((lane & 7) * 16) ^ ((lane >> 3) << 4);
    const int rsw = (li & 7) << 3;

    f32x4 acc[4][4];
    #pragma unroll
    for (int i = 0; i < 4; ++i)
        #pragma unroll
        for (int j = 0; j < 4; ++j)
            acc[i][j] = (f32x4){0.f, 0.f, 0.f, 0.f};

    for (int k0 = 0; k0 < ND; k0 += 64) {
        const int h = k0 >> 6;
        #pragma unroll
        for (int i = 0; i < 4; ++i) {
            const int r0 = (i * 4 + wv) * 8;
            const int gm = m0 + r0 + (lane >> 3);
            const int b_ = gm >> 11, sI = gm & 2047;
            gload_lds16((const char*)(Aq + (((size_t)(b_ * NH + h)) * NS + sI) * NHD) + gsw,
                        &As[r0 * 64]);
            if constexpr (BF)
                gload_lds16((const char*)(WbT + (size_t)(n0 + r0 + (lane >> 3)) * ND + k0) + gsw,
                            &Bs[r0 * 64]);
        }
        if constexpr (!BF) {
            #pragma unroll
            for (int i = 0; i < 4; ++i) {
                const int krow = 16 * i + (tid >> 4), ncol = (tid & 15) * 8;
                bf16x8 bv = load8f(Wf + (size_t)(k0 + krow) * ND + n0 + ncol);
                #pragma unroll
                for (int jj = 0; jj < 8; ++jj) {
                    const int n_ = ncol + jj;
                    Bs[n_ * 64 + ((((krow >> 3) ^ (n_ & 7)) << 3) | (krow & 7))] = (u16)bv[jj];
                }
            }
        }
        __syncthreads();

        bf16x8 a[4][2], b[4][2];
        #pragma unroll
        for (int i = 0; i < 4; ++i)
            #pragma unroll
            for (int kk = 0; kk < 2; ++kk)
                a[i][kk] = *(const bf16x8*)(&As[(wm * 64 + i * 16 + li) * 64 + ((kk * 32 + lg * 8) ^ rsw)]);
        #pragma unroll
        for (int j = 0; j < 4; ++j)
            #pragma unroll
            for (int kk = 0; kk < 2; ++kk)
                b[j][kk] = *(const bf16x8*)(&Bs[(wn * 64 + j * 16 + li) * 64 + ((kk * 32 + lg * 8) ^ rsw)]);
        #pragma unroll
        for (int i = 0; i < 4; ++i)
            #pragma unroll
            for (int j = 0; j < 4; ++j) {
                acc[i][j] = __builtin_amdgcn_mfma_f32_16x16x32_bf16(a[i][0], b[j][0], acc[i][j], 0, 0, 0);
                acc[i][j] = __builtin_amdgcn_mfma_f32_16x16x32_bf16(a[i][1], b[j][1], acc[i][j], 0, 0, 0);
            }
        __syncthreads();
    }

    #pragma unroll
    for (int i = 0; i < 4; ++i) {
      #pragma unroll
      for (int j = 0; j < 4; ++j) {
        const int gn = n0 + wn * 64 + j * 16 + li;
        const float bval = bias[gn];
        #pragma unroll
        for (int r = 0; r < 4; ++r) {
            const int gm = m0 + wm * 64 + i * 16 + lg * 4 + r;
            outp[(size_t)gm * ND + gn] = acc[i][j][r] + bval;
        }
      }
    }
}

// ---------------------------------------------------------------------------
extern "C" void kernel_launch(void* const* d_in, const int* in_sizes, int n_in,
                              void* d_out, int out_size, void* d_ws, size_t ws_size,
                              hipStream_t stream)
{
    const float* X    = (const float*)d_in[0];
    // d_in[1] = causal mask (bool) — deterministic triu(k=1), not read
    const float* Wqkv = (const float*)d_in[2];
    const float* bqkv = (const float*)d_in[3];
    const float* Wout = (const float*)d_in[4];
    const float* bout = (const float*)d_in[5];

    const size_t HE = (size_t)NB * NH * NS * NHD;   // 4,194,304

    float* out  = (float*)d_out;
    float* kout = out + HE;
    float* vout = kout + HE;

    u16* q_ws  = (u16*)d_ws;        // 8 MB: Q bf16 (pre-scaled) -> attn out
    u16* vT_ws = q_ws + HE;         // 8 MB: V^T bf16 [B,H,HD,S]
    u16* k_ws  = vT_ws + HE;        // 8 MB: K bf16 [B,H,S,HD]

    u16* Xb     = k_ws + HE;                    // 8 MB (dead after qkv)
    u16* WqkvT  = Xb + (size_t)NM * ND;         // 6 MB (dead after qkv)
    u16* WoutT  = WqkvT + (size_t)ND * N3;      // 2 MB (live until out_gemm)
    const bool big = ws_size >= (size_t)41943040;   // 40 MB

    if (big) {
        prep_cvt<<<dim3(6144), dim3(256), 0, stream>>>(X, Xb, Wqkv, WqkvT, Wout, WoutT);
        qkv_gemm<true><<<dim3(32 * 24), dim3(256), 0, stream>>>(
            X, Xb, Wqkv, WqkvT, bqkv, q_ws, vT_ws, k_ws, kout, vout);
    } else {
        qkv_gemm<false><<<dim3(32 * 24), dim3(256), 0, stream>>>(
            X, Xb, Wqkv, WqkvT, bqkv, q_ws, vT_ws, k_ws, kout, vout);
    }

    attn_fwd<<<dim3(1024), dim3(256), 0, stream>>>(q_ws, k_ws, vT_ws);

    if (big) {
        out_gemm<true><<<dim3(32 * 8), dim3(256), 0, stream>>>(
            q_ws, Wout, WoutT, bout, out);
    } else {
        out_gemm<false><<<dim3(32 * 8), dim3(256), 0, stream>>>(
            q_ws, Wout, WoutT, bout, out);
    }
}

// Round 10
// 115.190 us; speedup vs baseline: 2.1447x; 1.0940x over previous
//
#include <hip/hip_runtime.h>
#include <hip/hip_bf16.h>

typedef short bf16x8 __attribute__((ext_vector_type(8)));
typedef short u16x4v __attribute__((ext_vector_type(4)));
typedef float f32x4  __attribute__((ext_vector_type(4)));
typedef unsigned short u16;
typedef unsigned int   u32;

#define NB   2
#define NS   2048
#define ND   1024
#define NH   16
#define NHD  64
#define N3   3072
#define NM   4096   /* B*S */

__device__ __forceinline__ u16 f2bf(float f) {
    u32 u;
    __builtin_memcpy(&u, &f, 4);
    u += 0x7fffu + ((u >> 16) & 1u);
    return (u16)(u >> 16);
}
// Load 8 consecutive f32, convert RTNE to a bf16x8 fragment.
__device__ __forceinline__ bf16x8 load8f(const float* f) {
    float4 a = *(const float4*)f;
    float4 b = *(const float4*)(f + 4);
    bf16x8 r;
    r[0] = (short)f2bf(a.x); r[1] = (short)f2bf(a.y);
    r[2] = (short)f2bf(a.z); r[3] = (short)f2bf(a.w);
    r[4] = (short)f2bf(b.x); r[5] = (short)f2bf(b.y);
    r[6] = (short)f2bf(b.z); r[7] = (short)f2bf(b.w);
    return r;
}
// Async global->LDS, 16B per lane. LDS dest = wave-uniform base + lane*16.
__device__ __forceinline__ void gload_lds16(const void* g, void* l) {
    __builtin_amdgcn_global_load_lds(
        (const __attribute__((address_space(1))) u32*)g,
        (__attribute__((address_space(3))) u32*)l, 16, 0, 0);
}

// ---------------------------------------------------------------------------
// Kernel 0: prep — X f32->bf16 (blocks [0,2048)), Wqkv transpose+cvt
// ([2048,5120)), Wout transpose+cvt ([5120,6144)).
// ---------------------------------------------------------------------------
__global__ __launch_bounds__(256) void prep_cvt(
    const float* __restrict__ X, u16* __restrict__ Xb,
    const float* __restrict__ Wqkv, u16* __restrict__ WqkvT,
    const float* __restrict__ Wout, u16* __restrict__ WoutT)
{
    __shared__ float t[32][33];
    const int b = blockIdx.x;
    if (b < 2048) {
        const int i = (b * 256 + threadIdx.x) * 8;
        *(bf16x8*)(Xb + i) = load8f(X + i);
        return;
    }
    const float* in; u16* outp; int R, C, tIdx;
    if (b < 5120) { in = Wqkv; outp = WqkvT; R = ND; C = N3; tIdx = b - 2048; }
    else          { in = Wout; outp = WoutT; R = ND; C = ND; tIdx = b - 5120; }
    const int nbc = C >> 5;
    const int r0 = (tIdx / nbc) << 5;
    const int c0 = (tIdx % nbc) << 5;
    const int tr = threadIdx.x >> 3, tc = (threadIdx.x & 7) << 2;
    const float4 v = *(const float4*)(in + (size_t)(r0 + tr) * C + c0 + tc);
    t[tr][tc] = v.x; t[tr][tc + 1] = v.y; t[tr][tc + 2] = v.z; t[tr][tc + 3] = v.w;
    __syncthreads();
    u16x4v ov;
    ov[0] = (short)f2bf(t[tc + 0][tr]); ov[1] = (short)f2bf(t[tc + 1][tr]);
    ov[2] = (short)f2bf(t[tc + 2][tr]); ov[3] = (short)f2bf(t[tc + 3][tr]);
    *(u16x4v*)(outp + (size_t)(c0 + tr) * R + r0 + tc) = ov;
}

// ---------------------------------------------------------------------------
// Kernel 1: QKV projection, 128x128 tile / BK=64, double-buffered LDS with
// issue-early staging (T3-minimum 2-phase): STAGE(k+1) issues BEFORE the
// ds_read+MFMA of tile k, so HBM latency hides under compute. XOR-swizzled
// LDS. V-class blocks route vT_ws through a 32KB LDS transpose.
// ---------------------------------------------------------------------------
template<bool BF>
__global__ __launch_bounds__(256) void qkv_gemm(
    const float* __restrict__ Xf, const u16* __restrict__ Xb,
    const float* __restrict__ Wf, const u16* __restrict__ WbT,
    const float* __restrict__ bias,
    u16* __restrict__ q_ws, u16* __restrict__ vT_ws, u16* __restrict__ k_ws,
    float* __restrict__ k_out, float* __restrict__ v_out)
{
    __shared__ __align__(16) u16 As[2][128 * 64];   // 32 KB (swizzled)
    __shared__ __align__(16) u16 Bs[2][128 * 64];   // 32 KB (swizzled)

    const int bm = blockIdx.x & 31;        // 32 M-tiles
    const int bn = blockIdx.x >> 5;        // 24 N-tiles
    const int m0 = bm * 128, n0 = bn * 128;
    const int tid = threadIdx.x;
    const int lane = tid & 63, wv = tid >> 6;
    const int wm = wv >> 1, wn = wv & 1;
    const int li = lane & 15, lg = lane >> 4;
    const int gsw = ((lane & 7) * 16) ^ ((lane >> 3) << 4);  // staging byte col
    const int rsw = (li & 7) << 3;                           // read swz (u16)

    f32x4 acc[4][4];
    #pragma unroll
    for (int i = 0; i < 4; ++i)
        #pragma unroll
        for (int j = 0; j < 4; ++j)
            acc[i][j] = (f32x4){0.f, 0.f, 0.f, 0.f};

    auto stage = [&](int B, int k0) {
        if constexpr (BF) {
            #pragma unroll
            for (int i = 0; i < 4; ++i) {
                const int r0 = (i * 4 + wv) * 8;
                gload_lds16((const char*)(Xb  + (size_t)(m0 + r0 + (lane >> 3)) * ND + k0) + gsw, &As[B][r0 * 64]);
                gload_lds16((const char*)(WbT + (size_t)(n0 + r0 + (lane >> 3)) * ND + k0) + gsw, &Bs[B][r0 * 64]);
            }
        } else {
            #pragma unroll
            for (int i = 0; i < 4; ++i) {
                const int row = 32 * i + (tid >> 3), col = (tid & 7) * 8;
                *(bf16x8*)(&As[B][row * 64 + (col ^ ((row & 7) * 8))]) =
                    load8f(Xf + (size_t)(m0 + row) * ND + k0 + col);
            }
            #pragma unroll
            for (int i = 0; i < 4; ++i) {
                const int krow = 16 * i + (tid >> 4), ncol = (tid & 15) * 8;
                bf16x8 bv = load8f(Wf + (size_t)(k0 + krow) * N3 + n0 + ncol);
                #pragma unroll
                for (int jj = 0; jj < 8; ++jj) {
                    const int n_ = ncol + jj;
                    Bs[B][n_ * 64 + ((((krow >> 3) ^ (n_ & 7)) << 3) | (krow & 7))] = (u16)bv[jj];
                }
            }
        }
    };

    stage(0, 0);
    __syncthreads();              // tile 0 staged (vmcnt drained by barrier)

    int buf = 0;
    for (int k0 = 0; k0 < ND; k0 += 64) {
        if (k0 + 64 < ND) stage(buf ^ 1, k0 + 64);   // issue-early prefetch

        bf16x8 a[4][2], b[4][2];
        #pragma unroll
        for (int i = 0; i < 4; ++i)
            #pragma unroll
            for (int kk = 0; kk < 2; ++kk)
                a[i][kk] = *(const bf16x8*)(&As[buf][(wm * 64 + i * 16 + li) * 64 + ((kk * 32 + lg * 8) ^ rsw)]);
        #pragma unroll
        for (int j = 0; j < 4; ++j)
            #pragma unroll
            for (int kk = 0; kk < 2; ++kk)
                b[j][kk] = *(const bf16x8*)(&Bs[buf][(wn * 64 + j * 16 + li) * 64 + ((kk * 32 + lg * 8) ^ rsw)]);
        __builtin_amdgcn_s_setprio(1);
        #pragma unroll
        for (int i = 0; i < 4; ++i)
            #pragma unroll
            for (int j = 0; j < 4; ++j) {
                acc[i][j] = __builtin_amdgcn_mfma_f32_16x16x32_bf16(a[i][0], b[j][0], acc[i][j], 0, 0, 0);
                acc[i][j] = __builtin_amdgcn_mfma_f32_16x16x32_bf16(a[i][1], b[j][1], acc[i][j], 0, 0, 0);
            }
        __builtin_amdgcn_s_setprio(0);

        __syncthreads();          // next tile staged + this buf free for reuse
        buf ^= 1;
    }

    const int cls = bn >> 3;   // 0=Q, 1=K, 2=V
    if (cls == 2) {
        u16* SM = &As[0][0];   // 32 KB contiguous, staging dead
        // f32 output direct; bf16 into LDS transposed [n][m] (XOR-swizzled m)
        #pragma unroll
        for (int i = 0; i < 4; ++i) {
          #pragma unroll
          for (int j = 0; j < 4; ++j) {
            const int gn = n0 + wn * 64 + j * 16 + li;
            const float bval = bias[gn];
            const int c = gn & 1023, h = c >> 6, d = c & 63;
            const int n_ = wn * 64 + j * 16 + li;
            #pragma unroll
            for (int r = 0; r < 4; ++r) {
                const int gm = m0 + wm * 64 + i * 16 + lg * 4 + r;
                const int b_ = gm >> 11, sI = gm & 2047;
                const float v = acc[i][j][r] + bval;
                v_out[(((size_t)(b_ * NH + h)) * NS + sI) * NHD + d] = v;
                const int m_ = wm * 64 + i * 16 + lg * 4 + r;
                SM[n_ * 128 + (m_ ^ ((n_ & 7) << 3))] = f2bf(v);
            }
          }
        }
        __syncthreads();
        const int nrow = tid >> 1, mh = tid & 1;
        const int cdx = (n0 - 2048) + nrow;           // V col 0..1023
        const int hh = cdx >> 6, d = cdx & 63;
        const int b_ = m0 >> 11;
        const int s0 = (m0 & 2047) + mh * 64;
        u16* dst = vT_ws + (((size_t)(b_ * NH + hh)) * NHD + d) * NS + s0;
        #pragma unroll
        for (int c8 = 0; c8 < 8; ++c8) {
            const int m_ = mh * 64 + c8 * 8;
            *(bf16x8*)(dst + c8 * 8) =
                *(const bf16x8*)(&SM[nrow * 128 + (m_ ^ ((nrow & 7) << 3))]);
        }
    } else {
        #pragma unroll
        for (int i = 0; i < 4; ++i) {
          #pragma unroll
          for (int j = 0; j < 4; ++j) {
            const int gn = n0 + wn * 64 + j * 16 + li;
            const float bval = bias[gn];
            const int c = gn & 1023, h = c >> 6, d = c & 63;
            #pragma unroll
            for (int r = 0; r < 4; ++r) {
                const int gm = m0 + wm * 64 + i * 16 + lg * 4 + r;
                const int b_ = gm >> 11, sI = gm & 2047;
                const float v = acc[i][j][r] + bval;
                const size_t hidx = (((size_t)(b_ * NH + h)) * NS + sI) * NHD + d;
                if (cls == 0) {
                    q_ws[hidx] = f2bf(v * 0.125f);
                } else {
                    k_out[hidx] = v;
                    k_ws[hidx] = f2bf(v);
                }
            }
          }
        }
    }
}

// ---------------------------------------------------------------------------
// Kernel 2: causal flash attention. One 64-row q-tile per block, 1024 blocks,
// KBLK=64 double-buffered LDS K/V^T. Complementary-tile XCD swizzle: per XCD
// j in [0,128), head = j>>5, tile = (j>>5&1) ? 31-(j&31) : (j&31) -> each CU
// gets tiles {c, 31-c, c, 31-c} = 66 tile-units, uniform, 4 heads/XCD kept.
// LDS 40960B -> 4 blocks/CU. Deferred max (exact), ones-MFMA row-sum.
// ---------------------------------------------------------------------------
__global__ __launch_bounds__(256, 4) void attn_fwd(
    u16* __restrict__ q_all, const u16* __restrict__ k_all,
    const u16* __restrict__ vT)
{
    __shared__ __align__(16) u16 Ks[2][64 * 64];
    __shared__ __align__(16) u16 Vs[2][64 * 64];
    __shared__ __align__(16) u16 Pl[4][16 * 64];   // XOR-swizzled

    const int tid = threadIdx.x;
    const int wv = tid >> 6, lane = tid & 63;
    const int li = lane & 15, lg = lane >> 4;
    const int bid = blockIdx.x;                 // 1024
    const int xcd = bid & 7, j = bid >> 3;      // j in 0..127 per XCD
    const int bh  = (xcd << 2) | (j >> 5);      // 4 heads per XCD
    const int jj  = j & 31;
    const int qt  = (j & 32) ? (31 - jj) : jj;  // complementary per CU
    const int q0  = qt * 64 + wv * 16;
    const int ntiles = qt + 1;

    u16* qp = q_all + (size_t)bh * NS * NHD;    // read Q, later write O (alias)
    const u16* kp = k_all + (size_t)bh * NS * NHD;
    const u16* vp = vT + (size_t)bh * NHD * NS;

    const int rl = lane >> 3;
    const int gsw = ((lane & 7) * 16) ^ (rl << 4);  // pre-swizzled byte col
    const int rs = (li & 7) << 3;                   // u16-unit read swizzle

    bf16x8 aq0 = *(const bf16x8*)(qp + (size_t)(q0 + li) * NHD + lg * 8);
    bf16x8 aq1 = *(const bf16x8*)(qp + (size_t)(q0 + li) * NHD + 32 + lg * 8);

    f32x4 o[4], ls;
    ls = (f32x4){0.f, 0.f, 0.f, 0.f};
    #pragma unroll
    for (int nf = 0; nf < 4; ++nf) o[nf] = (f32x4){0.f, 0.f, 0.f, 0.f};
    float m = 4.0f;   // deferred-max baseline; exact (common scale of O and l)

    const short onb = (short)0x3F80;
    const bf16x8 ones = {onb, onb, onb, onb, onb, onb, onb, onb};

    #define STAGE(B, KB) do {                                                           \
        _Pragma("unroll")                                                               \
        for (int i_ = 0; i_ < 2; ++i_) {                                                \
            const int row_ = 16 * wv + 8 * i_;                                          \
            gload_lds16((const char*)(kp + (size_t)((KB) + row_ + rl) * NHD) + gsw,     \
                        &Ks[B][row_ * 64]);                                             \
            gload_lds16((const char*)(vp + (size_t)(row_ + rl) * NS + (KB)) + gsw,      \
                        &Vs[B][row_ * 64]);                                             \
        } } while (0)

    STAGE(0, 0);
    __syncthreads();

    int buf = 0;
    for (int kt = 0; kt < ntiles; ++kt) {
        const int kb = kt * 64;
        if (kt + 1 < ntiles) STAGE(buf ^ 1, kb + 64);

        const u16* K = Ks[buf];
        const u16* V = Vs[buf];

        // QK^T: s[kq] rows q0+lg*4+r, key col kq*16+li
        f32x4 s[4];
        __builtin_amdgcn_s_setprio(1);
        #pragma unroll
        for (int kq = 0; kq < 4; ++kq) {
            const u16* Kr = K + (kq * 16 + li) * 64;
            const bf16x8 b0 = *(const bf16x8*)(Kr + ((lg * 8) ^ rs));
            const bf16x8 b1 = *(const bf16x8*)(Kr + ((lg * 8 + 32) ^ rs));
            f32x4 t = (f32x4){0.f, 0.f, 0.f, 0.f};
            t = __builtin_amdgcn_mfma_f32_16x16x32_bf16(aq0, b0, t, 0, 0, 0);
            s[kq] = __builtin_amdgcn_mfma_f32_16x16x32_bf16(aq1, b1, t, 0, 0, 0);
        }
        __builtin_amdgcn_s_setprio(0);

        // deferred max: per-lane tree + wave vote; reduce only on trigger
        float mx = s[0][0];
        #pragma unroll
        for (int kq = 0; kq < 4; ++kq)
            #pragma unroll
            for (int r = 0; r < 4; ++r)
                mx = fmaxf(mx, s[kq][r]);
        if (__any(mx > m)) {
            #pragma unroll
            for (int dd = 1; dd < 64; dd <<= 1)
                mx = fmaxf(mx, __shfl_xor(mx, dd, 64));
            const float corr = __expf(m - mx);
            m = mx;
            #pragma unroll
            for (int nf = 0; nf < 4; ++nf)
                #pragma unroll
                for (int r = 0; r < 4; ++r) o[nf][r] *= corr;
            #pragma unroll
            for (int r = 0; r < 4; ++r) ls[r] *= corr;
        }

        // V fragments
        bf16x8 vf[4][2];
        #pragma unroll
        for (int nf = 0; nf < 4; ++nf) {
            const u16* Vr = V + (nf * 16 + li) * 64;
            vf[nf][0] = *(const bf16x8*)(Vr + ((lg * 8) ^ rs));
            vf[nf][1] = *(const bf16x8*)(Vr + ((lg * 8 + 32) ^ rs));
        }

        // P = exp(s-m) -> LDS (swizzled); mask on last tile only
        const bool maskt = (kt == ntiles - 1);
        u16* PW = Pl[wv];
        #pragma unroll
        for (int r = 0; r < 4; ++r) {
            const int q_ = lg * 4 + r;
            const int qrow = q0 + q_;
            const int qm = q_ & 7;
            #pragma unroll
            for (int kq = 0; kq < 4; ++kq) {
                float ev = __expf(s[kq][r] - m);
                if (maskt && (kb + kq * 16 + li > qrow)) ev = 0.f;
                PW[q_ * 64 + ((((2 * kq + (li >> 3)) ^ qm) << 3) | (li & 7))] = f2bf(ev);
            }
        }
        asm volatile("s_waitcnt lgkmcnt(0)" ::: "memory");
        const bf16x8 pa0 = *(const bf16x8*)(PW + li * 64 + ((lg ^ (li & 7)) << 3));
        const bf16x8 pa1 = *(const bf16x8*)(PW + li * 64 + (((lg + 4) ^ (li & 7)) << 3));
        __builtin_amdgcn_s_setprio(1);
        #pragma unroll
        for (int nf = 0; nf < 4; ++nf) {
            f32x4 t = __builtin_amdgcn_mfma_f32_16x16x32_bf16(pa0, vf[nf][0], o[nf], 0, 0, 0);
            o[nf] = __builtin_amdgcn_mfma_f32_16x16x32_bf16(pa1, vf[nf][1], t, 0, 0, 0);
        }
        ls = __builtin_amdgcn_mfma_f32_16x16x32_bf16(pa0, ones, ls, 0, 0, 0);
        ls = __builtin_amdgcn_mfma_f32_16x16x32_bf16(pa1, ones, ls, 0, 0, 0);
        __builtin_amdgcn_s_setprio(0);

        __syncthreads();   // prefetch arrived + P/K/V buffer reuse safe
        buf ^= 1;
    }

    #pragma unroll
    for (int nf = 0; nf < 4; ++nf)
        #pragma unroll
        for (int r = 0; r < 4; ++r)
            qp[(size_t)(q0 + lg * 4 + r) * NHD + nf * 16 + li] = f2bf(o[nf][r] / ls[r]);
    #undef STAGE
}

// ---------------------------------------------------------------------------
// Kernel 3: output projection, 128x128 / BK=64, double-buffered issue-early
// staging, XOR-swizzled LDS. A = attn output in q_ws ([B,H,S,HD] permuted).
// ---------------------------------------------------------------------------
template<bool BF>
__global__ __launch_bounds__(256) void out_gemm(
    const u16* __restrict__ Aq,
    const float* __restrict__ Wf, const u16* __restrict__ WbT,
    const float* __restrict__ bias, float* __restrict__ outp)
{
    __shared__ __align__(16) u16 As[2][128 * 64];
    __shared__ __align__(16) u16 Bs[2][128 * 64];

    const int bm = blockIdx.x & 31;
    const int bn = blockIdx.x >> 5;        // 8 N-tiles
    const int m0 = bm * 128, n0 = bn * 128;
    const int tid = threadIdx.x;
    const int lane = tid & 63, wv = tid >> 6;
    const int wm = wv >> 1, wn = wv & 1;
    const int li = lane & 15, lg = lane >> 4;
    const int gsw = ((lane & 7) * 16) ^ ((lane >> 3) << 4);
    const int rsw = (li & 7) << 3;

    f32x4 acc[4][4];
    #pragma unroll
    for (int i = 0; i < 4; ++i)
        #pragma unroll
        for (int j = 0; j < 4; ++j)
            acc[i][j] = (f32x4){0.f, 0.f, 0.f, 0.f};

    auto stage = [&](int B, int k0) {
        const int h = k0 >> 6;
        #pragma unroll
        for (int i = 0; i < 4; ++i) {
            const int r0 = (i * 4 + wv) * 8;
            const int gm = m0 + r0 + (lane >> 3);
            const int b_ = gm >> 11, sI = gm & 2047;
            gload_lds16((const char*)(Aq + (((size_t)(b_ * NH + h)) * NS + sI) * NHD) + gsw,
                        &As[B][r0 * 64]);
            if constexpr (BF)
                gload_lds16((const char*)(WbT + (size_t)(n0 + r0 + (lane >> 3)) * ND + k0) + gsw,
                            &Bs[B][r0 * 64]);
        }
        if constexpr (!BF) {
            #pragma unroll
            for (int i = 0; i < 4; ++i) {
                const int krow = 16 * i + (tid >> 4), ncol = (tid & 15) * 8;
                bf16x8 bv = load8f(Wf + (size_t)(k0 + krow) * ND + n0 + ncol);
                #pragma unroll
                for (int jj = 0; jj < 8; ++jj) {
                    const int n_ = ncol + jj;
                    Bs[B][n_ * 64 + ((((krow >> 3) ^ (n_ & 7)) << 3) | (krow & 7))] = (u16)bv[jj];
                }
            }
        }
    };

    stage(0, 0);
    __syncthreads();

    int buf = 0;
    for (int k0 = 0; k0 < ND; k0 += 64) {
        if (k0 + 64 < ND) stage(buf ^ 1, k0 + 64);

        bf16x8 a[4][2], b[4][2];
        #pragma unroll
        for (int i = 0; i < 4; ++i)
            #pragma unroll
            for (int kk = 0; kk < 2; ++kk)
                a[i][kk] = *(const bf16x8*)(&As[buf][(wm * 64 + i * 16 + li) * 64 + ((kk * 32 + lg * 8) ^ rsw)]);
        #pragma unroll
        for (int j = 0; j < 4; ++j)
            #pragma unroll
            for (int kk = 0; kk < 2; ++kk)
                b[j][kk] = *(const bf16x8*)(&Bs[buf][(wn * 64 + j * 16 + li) * 64 + ((kk * 32 + lg * 8) ^ rsw)]);
        __builtin_amdgcn_s_setprio(1);
        #pragma unroll
        for (int i = 0; i < 4; ++i)
            #pragma unroll
            for (int j = 0; j < 4; ++j) {
                acc[i][j] = __builtin_amdgcn_mfma_f32_16x16x32_bf16(a[i][0], b[j][0], acc[i][j], 0, 0, 0);
                acc[i][j] = __builtin_amdgcn_mfma_f32_16x16x32_bf16(a[i][1], b[j][1], acc[i][j], 0, 0, 0);
            }
        __builtin_amdgcn_s_setprio(0);

        __syncthreads();
        buf ^= 1;
    }

    #pragma unroll
    for (int i = 0; i < 4; ++i) {
      #pragma unroll
      for (int j = 0; j < 4; ++j) {
        const int gn = n0 + wn * 64 + j * 16 + li;
        const float bval = bias[gn];
        #pragma unroll
        for (int r = 0; r < 4; ++r) {
            const int gm = m0 + wm * 64 + i * 16 + lg * 4 + r;
            outp[(size_t)gm * ND + gn] = acc[i][j][r] + bval;
        }
      }
    }
}

// ---------------------------------------------------------------------------
extern "C" void kernel_launch(void* const* d_in, const int* in_sizes, int n_in,
                              void* d_out, int out_size, void* d_ws, size_t ws_size,
                              hipStream_t stream)
{
    const float* X    = (const float*)d_in[0];
    // d_in[1] = causal mask (bool) — deterministic triu(k=1), not read
    const float* Wqkv = (const float*)d_in[2];
    const float* bqkv = (const float*)d_in[3];
    const float* Wout = (const float*)d_in[4];
    const float* bout = (const float*)d_in[5];

    const size_t HE = (size_t)NB * NH * NS * NHD;   // 4,194,304

    float* out  = (float*)d_out;
    float* kout = out + HE;
    float* vout = kout + HE;

    u16* q_ws  = (u16*)d_ws;        // 8 MB: Q bf16 (pre-scaled) -> attn out
    u16* vT_ws = q_ws + HE;         // 8 MB: V^T bf16 [B,H,HD,S]
    u16* k_ws  = vT_ws + HE;        // 8 MB: K bf16 [B,H,S,HD]

    u16* Xb     = k_ws + HE;                    // 8 MB (dead after qkv)
    u16* WqkvT  = Xb + (size_t)NM * ND;         // 6 MB (dead after qkv)
    u16* WoutT  = WqkvT + (size_t)ND * N3;      // 2 MB (live until out_gemm)
    const bool big = ws_size >= (size_t)41943040;   // 40 MB

    if (big) {
        prep_cvt<<<dim3(6144), dim3(256), 0, stream>>>(X, Xb, Wqkv, WqkvT, Wout, WoutT);
        qkv_gemm<true><<<dim3(32 * 24), dim3(256), 0, stream>>>(
            X, Xb, Wqkv, WqkvT, bqkv, q_ws, vT_ws, k_ws, kout, vout);
    } else {
        qkv_gemm<false><<<dim3(32 * 24), dim3(256), 0, stream>>>(
            X, Xb, Wqkv, WqkvT, bqkv, q_ws, vT_ws, k_ws, kout, vout);
    }

    attn_fwd<<<dim3(1024), dim3(256), 0, stream>>>(q_ws, k_ws, vT_ws);

    if (big) {
        out_gemm<true><<<dim3(32 * 8), dim3(256), 0, stream>>>(
            q_ws, Wout, WoutT, bout, out);
    } else {
        out_gemm<false><<<dim3(32 * 8), dim3(256), 0, stream>>>(
            q_ws, Wout, WoutT, bout, out);
    }
}

// Round 11
// 115.091 us; speedup vs baseline: 2.1465x; 1.0009x over previous
//
#include <hip/hip_runtime.h>
#include <hip/hip_bf16.h>

typedef short bf16x8 __attribute__((ext_vector_type(8)));
typedef short u16x4v __attribute__((ext_vector_type(4)));
typedef float f32x4  __attribute__((ext_vector_type(4)));
typedef unsigned short u16;
typedef unsigned int   u32;

#define NB   2
#define NS   2048
#define ND   1024
#define NH   16
#define NHD  64
#define N3   3072
#define NM   4096   /* B*S */

__device__ __forceinline__ u16 f2bf(float f) {
    u32 u;
    __builtin_memcpy(&u, &f, 4);
    u += 0x7fffu + ((u >> 16) & 1u);
    return (u16)(u >> 16);
}
// Load 8 consecutive f32, convert RTNE to a bf16x8 fragment.
__device__ __forceinline__ bf16x8 load8f(const float* f) {
    float4 a = *(const float4*)f;
    float4 b = *(const float4*)(f + 4);
    bf16x8 r;
    r[0] = (short)f2bf(a.x); r[1] = (short)f2bf(a.y);
    r[2] = (short)f2bf(a.z); r[3] = (short)f2bf(a.w);
    r[4] = (short)f2bf(b.x); r[5] = (short)f2bf(b.y);
    r[6] = (short)f2bf(b.z); r[7] = (short)f2bf(b.w);
    return r;
}
// Async global->LDS, 16B per lane. LDS dest = wave-uniform base + lane*16.
__device__ __forceinline__ void gload_lds16(const void* g, void* l) {
    __builtin_amdgcn_global_load_lds(
        (const __attribute__((address_space(1))) u32*)g,
        (__attribute__((address_space(3))) u32*)l, 16, 0, 0);
}

// ---------------------------------------------------------------------------
// Kernel 0: prep — X f32->bf16 (blocks [0,2048)), Wqkv transpose+cvt
// ([2048,5120)), Wout transpose+cvt ([5120,6144)).
// ---------------------------------------------------------------------------
__global__ __launch_bounds__(256) void prep_cvt(
    const float* __restrict__ X, u16* __restrict__ Xb,
    const float* __restrict__ Wqkv, u16* __restrict__ WqkvT,
    const float* __restrict__ Wout, u16* __restrict__ WoutT)
{
    __shared__ float t[32][33];
    const int b = blockIdx.x;
    if (b < 2048) {
        const int i = (b * 256 + threadIdx.x) * 8;
        *(bf16x8*)(Xb + i) = load8f(X + i);
        return;
    }
    const float* in; u16* outp; int R, C, tIdx;
    if (b < 5120) { in = Wqkv; outp = WqkvT; R = ND; C = N3; tIdx = b - 2048; }
    else          { in = Wout; outp = WoutT; R = ND; C = ND; tIdx = b - 5120; }
    const int nbc = C >> 5;
    const int r0 = (tIdx / nbc) << 5;
    const int c0 = (tIdx % nbc) << 5;
    const int tr = threadIdx.x >> 3, tc = (threadIdx.x & 7) << 2;
    const float4 v = *(const float4*)(in + (size_t)(r0 + tr) * C + c0 + tc);
    t[tr][tc] = v.x; t[tr][tc + 1] = v.y; t[tr][tc + 2] = v.z; t[tr][tc + 3] = v.w;
    __syncthreads();
    u16x4v ov;
    ov[0] = (short)f2bf(t[tc + 0][tr]); ov[1] = (short)f2bf(t[tc + 1][tr]);
    ov[2] = (short)f2bf(t[tc + 2][tr]); ov[3] = (short)f2bf(t[tc + 3][tr]);
    *(u16x4v*)(outp + (size_t)(c0 + tr) * R + r0 + tc) = ov;
}

// ---------------------------------------------------------------------------
// Kernel 1: QKV projection, 128x128 tile / BK=64, double-buffered LDS with
// issue-early staging (T3-minimum 2-phase): STAGE(k+1) issues BEFORE the
// ds_read+MFMA of tile k, so HBM latency hides under compute. XOR-swizzled
// LDS. V-class blocks route vT_ws through a 32KB LDS transpose.
// ---------------------------------------------------------------------------
template<bool BF>
__global__ __launch_bounds__(256) void qkv_gemm(
    const float* __restrict__ Xf, const u16* __restrict__ Xb,
    const float* __restrict__ Wf, const u16* __restrict__ WbT,
    const float* __restrict__ bias,
    u16* __restrict__ q_ws, u16* __restrict__ vT_ws, u16* __restrict__ k_ws,
    float* __restrict__ k_out, float* __restrict__ v_out)
{
    __shared__ __align__(16) u16 As[2][128 * 64];   // 32 KB (swizzled)
    __shared__ __align__(16) u16 Bs[2][128 * 64];   // 32 KB (swizzled)

    const int bm = blockIdx.x & 31;        // 32 M-tiles
    const int bn = blockIdx.x >> 5;        // 24 N-tiles
    const int m0 = bm * 128, n0 = bn * 128;
    const int tid = threadIdx.x;
    const int lane = tid & 63, wv = tid >> 6;
    const int wm = wv >> 1, wn = wv & 1;
    const int li = lane & 15, lg = lane >> 4;
    const int gsw = ((lane & 7) * 16) ^ ((lane >> 3) << 4);  // staging byte col
    const int rsw = (li & 7) << 3;                           // read swz (u16)

    f32x4 acc[4][4];
    #pragma unroll
    for (int i = 0; i < 4; ++i)
        #pragma unroll
        for (int j = 0; j < 4; ++j)
            acc[i][j] = (f32x4){0.f, 0.f, 0.f, 0.f};

    auto stage = [&](int B, int k0) {
        if constexpr (BF) {
            #pragma unroll
            for (int i = 0; i < 4; ++i) {
                const int r0 = (i * 4 + wv) * 8;
                gload_lds16((const char*)(Xb  + (size_t)(m0 + r0 + (lane >> 3)) * ND + k0) + gsw, &As[B][r0 * 64]);
                gload_lds16((const char*)(WbT + (size_t)(n0 + r0 + (lane >> 3)) * ND + k0) + gsw, &Bs[B][r0 * 64]);
            }
        } else {
            #pragma unroll
            for (int i = 0; i < 4; ++i) {
                const int row = 32 * i + (tid >> 3), col = (tid & 7) * 8;
                *(bf16x8*)(&As[B][row * 64 + (col ^ ((row & 7) * 8))]) =
                    load8f(Xf + (size_t)(m0 + row) * ND + k0 + col);
            }
            #pragma unroll
            for (int i = 0; i < 4; ++i) {
                const int krow = 16 * i + (tid >> 4), ncol = (tid & 15) * 8;
                bf16x8 bv = load8f(Wf + (size_t)(k0 + krow) * N3 + n0 + ncol);
                #pragma unroll
                for (int jj = 0; jj < 8; ++jj) {
                    const int n_ = ncol + jj;
                    Bs[B][n_ * 64 + ((((krow >> 3) ^ (n_ & 7)) << 3) | (krow & 7))] = (u16)bv[jj];
                }
            }
        }
    };

    stage(0, 0);
    __syncthreads();              // tile 0 staged (vmcnt drained by barrier)

    int buf = 0;
    for (int k0 = 0; k0 < ND; k0 += 64) {
        if (k0 + 64 < ND) stage(buf ^ 1, k0 + 64);   // issue-early prefetch

        bf16x8 a[4][2], b[4][2];
        #pragma unroll
        for (int i = 0; i < 4; ++i)
            #pragma unroll
            for (int kk = 0; kk < 2; ++kk)
                a[i][kk] = *(const bf16x8*)(&As[buf][(wm * 64 + i * 16 + li) * 64 + ((kk * 32 + lg * 8) ^ rsw)]);
        #pragma unroll
        for (int j = 0; j < 4; ++j)
            #pragma unroll
            for (int kk = 0; kk < 2; ++kk)
                b[j][kk] = *(const bf16x8*)(&Bs[buf][(wn * 64 + j * 16 + li) * 64 + ((kk * 32 + lg * 8) ^ rsw)]);
        __builtin_amdgcn_s_setprio(1);
        #pragma unroll
        for (int i = 0; i < 4; ++i)
            #pragma unroll
            for (int j = 0; j < 4; ++j) {
                acc[i][j] = __builtin_amdgcn_mfma_f32_16x16x32_bf16(a[i][0], b[j][0], acc[i][j], 0, 0, 0);
                acc[i][j] = __builtin_amdgcn_mfma_f32_16x16x32_bf16(a[i][1], b[j][1], acc[i][j], 0, 0, 0);
            }
        __builtin_amdgcn_s_setprio(0);

        __syncthreads();          // next tile staged + this buf free for reuse
        buf ^= 1;
    }

    const int cls = bn >> 3;   // 0=Q, 1=K, 2=V
    if (cls == 2) {
        u16* SM = &As[0][0];   // 32 KB contiguous, staging dead
        // f32 output direct; bf16 into LDS transposed [n][m] (XOR-swizzled m)
        #pragma unroll
        for (int i = 0; i < 4; ++i) {
          #pragma unroll
          for (int j = 0; j < 4; ++j) {
            const int gn = n0 + wn * 64 + j * 16 + li;
            const float bval = bias[gn];
            const int c = gn & 1023, h = c >> 6, d = c & 63;
            const int n_ = wn * 64 + j * 16 + li;
            #pragma unroll
            for (int r = 0; r < 4; ++r) {
                const int gm = m0 + wm * 64 + i * 16 + lg * 4 + r;
                const int b_ = gm >> 11, sI = gm & 2047;
                const float v = acc[i][j][r] + bval;
                v_out[(((size_t)(b_ * NH + h)) * NS + sI) * NHD + d] = v;
                const int m_ = wm * 64 + i * 16 + lg * 4 + r;
                SM[n_ * 128 + (m_ ^ ((n_ & 7) << 3))] = f2bf(v);
            }
          }
        }
        __syncthreads();
        const int nrow = tid >> 1, mh = tid & 1;
        const int cdx = (n0 - 2048) + nrow;           // V col 0..1023
        const int hh = cdx >> 6, d = cdx & 63;
        const int b_ = m0 >> 11;
        const int s0 = (m0 & 2047) + mh * 64;
        u16* dst = vT_ws + (((size_t)(b_ * NH + hh)) * NHD + d) * NS + s0;
        #pragma unroll
        for (int c8 = 0; c8 < 8; ++c8) {
            const int m_ = mh * 64 + c8 * 8;
            *(bf16x8*)(dst + c8 * 8) =
                *(const bf16x8*)(&SM[nrow * 128 + (m_ ^ ((nrow & 7) << 3))]);
        }
    } else {
        #pragma unroll
        for (int i = 0; i < 4; ++i) {
          #pragma unroll
          for (int j = 0; j < 4; ++j) {
            const int gn = n0 + wn * 64 + j * 16 + li;
            const float bval = bias[gn];
            const int c = gn & 1023, h = c >> 6, d = c & 63;
            #pragma unroll
            for (int r = 0; r < 4; ++r) {
                const int gm = m0 + wm * 64 + i * 16 + lg * 4 + r;
                const int b_ = gm >> 11, sI = gm & 2047;
                const float v = acc[i][j][r] + bval;
                const size_t hidx = (((size_t)(b_ * NH + h)) * NS + sI) * NHD + d;
                if (cls == 0) {
                    q_ws[hidx] = f2bf(v * 0.125f);
                } else {
                    k_out[hidx] = v;
                    k_ws[hidx] = f2bf(v);
                }
            }
          }
        }
    }
}

// ---------------------------------------------------------------------------
// Kernel 2: causal flash attention. One 64-row q-tile per block, 1024 blocks,
// KBLK=64 double-buffered LDS K/V^T. Complementary-tile XCD swizzle: per XCD
// j in [0,128), head = j>>5, tile = (j>>5&1) ? 31-(j&31) : (j&31) -> each CU
// gets tiles {c, 31-c, c, 31-c} = 66 tile-units, uniform, 4 heads/XCD kept.
// LDS 40960B -> 4 blocks/CU. Deferred max (exact), ones-MFMA row-sum.
// ---------------------------------------------------------------------------
__global__ __launch_bounds__(256, 4) void attn_fwd(
    u16* __restrict__ q_all, const u16* __restrict__ k_all,
    const u16* __restrict__ vT)
{
    __shared__ __align__(16) u16 Ks[2][64 * 64];
    __shared__ __align__(16) u16 Vs[2][64 * 64];
    __shared__ __align__(16) u16 Pl[4][16 * 64];   // XOR-swizzled

    const int tid = threadIdx.x;
    const int wv = tid >> 6, lane = tid & 63;
    const int li = lane & 15, lg = lane >> 4;
    const int bid = blockIdx.x;                 // 1024
    const int xcd = bid & 7, j = bid >> 3;      // j in 0..127 per XCD
    const int bh  = (xcd << 2) | (j >> 5);      // 4 heads per XCD
    const int jj  = j & 31;
    const int qt  = (j & 32) ? (31 - jj) : jj;  // complementary per CU
    const int q0  = qt * 64 + wv * 16;
    const int ntiles = qt + 1;

    u16* qp = q_all + (size_t)bh * NS * NHD;    // read Q, later write O (alias)
    const u16* kp = k_all + (size_t)bh * NS * NHD;
    const u16* vp = vT + (size_t)bh * NHD * NS;

    const int rl = lane >> 3;
    const int gsw = ((lane & 7) * 16) ^ (rl << 4);  // pre-swizzled byte col
    const int rs = (li & 7) << 3;                   // u16-unit read swizzle

    bf16x8 aq0 = *(const bf16x8*)(qp + (size_t)(q0 + li) * NHD + lg * 8);
    bf16x8 aq1 = *(const bf16x8*)(qp + (size_t)(q0 + li) * NHD + 32 + lg * 8);

    f32x4 o[4], ls;
    ls = (f32x4){0.f, 0.f, 0.f, 0.f};
    #pragma unroll
    for (int nf = 0; nf < 4; ++nf) o[nf] = (f32x4){0.f, 0.f, 0.f, 0.f};
    float m = 4.0f;   // deferred-max baseline; exact (common scale of O and l)

    const short onb = (short)0x3F80;
    const bf16x8 ones = {onb, onb, onb, onb, onb, onb, onb, onb};

    #define STAGE(B, KB) do {                                                           \
        _Pragma("unroll")                                                               \
        for (int i_ = 0; i_ < 2; ++i_) {                                                \
            const int row_ = 16 * wv + 8 * i_;                                          \
            gload_lds16((const char*)(kp + (size_t)((KB) + row_ + rl) * NHD) + gsw,     \
                        &Ks[B][row_ * 64]);                                             \
            gload_lds16((const char*)(vp + (size_t)(row_ + rl) * NS + (KB)) + gsw,      \
                        &Vs[B][row_ * 64]);                                             \
        } } while (0)

    STAGE(0, 0);
    __syncthreads();

    int buf = 0;
    for (int kt = 0; kt < ntiles; ++kt) {
        const int kb = kt * 64;
        if (kt + 1 < ntiles) STAGE(buf ^ 1, kb + 64);

        const u16* K = Ks[buf];
        const u16* V = Vs[buf];

        // QK^T: s[kq] rows q0+lg*4+r, key col kq*16+li
        f32x4 s[4];
        __builtin_amdgcn_s_setprio(1);
        #pragma unroll
        for (int kq = 0; kq < 4; ++kq) {
            const u16* Kr = K + (kq * 16 + li) * 64;
            const bf16x8 b0 = *(const bf16x8*)(Kr + ((lg * 8) ^ rs));
            const bf16x8 b1 = *(const bf16x8*)(Kr + ((lg * 8 + 32) ^ rs));
            f32x4 t = (f32x4){0.f, 0.f, 0.f, 0.f};
            t = __builtin_amdgcn_mfma_f32_16x16x32_bf16(aq0, b0, t, 0, 0, 0);
            s[kq] = __builtin_amdgcn_mfma_f32_16x16x32_bf16(aq1, b1, t, 0, 0, 0);
        }
        __builtin_amdgcn_s_setprio(0);

        // deferred max: per-lane tree + wave vote; reduce only on trigger
        float mx = s[0][0];
        #pragma unroll
        for (int kq = 0; kq < 4; ++kq)
            #pragma unroll
            for (int r = 0; r < 4; ++r)
                mx = fmaxf(mx, s[kq][r]);
        if (__any(mx > m)) {
            #pragma unroll
            for (int dd = 1; dd < 64; dd <<= 1)
                mx = fmaxf(mx, __shfl_xor(mx, dd, 64));
            const float corr = __expf(m - mx);
            m = mx;
            #pragma unroll
            for (int nf = 0; nf < 4; ++nf)
                #pragma unroll
                for (int r = 0; r < 4; ++r) o[nf][r] *= corr;
            #pragma unroll
            for (int r = 0; r < 4; ++r) ls[r] *= corr;
        }

        // V fragments
        bf16x8 vf[4][2];
        #pragma unroll
        for (int nf = 0; nf < 4; ++nf) {
            const u16* Vr = V + (nf * 16 + li) * 64;
            vf[nf][0] = *(const bf16x8*)(Vr + ((lg * 8) ^ rs));
            vf[nf][1] = *(const bf16x8*)(Vr + ((lg * 8 + 32) ^ rs));
        }

        // P = exp(s-m) -> LDS (swizzled); mask on last tile only
        const bool maskt = (kt == ntiles - 1);
        u16* PW = Pl[wv];
        #pragma unroll
        for (int r = 0; r < 4; ++r) {
            const int q_ = lg * 4 + r;
            const int qrow = q0 + q_;
            const int qm = q_ & 7;
            #pragma unroll
            for (int kq = 0; kq < 4; ++kq) {
                float ev = __expf(s[kq][r] - m);
                if (maskt && (kb + kq * 16 + li > qrow)) ev = 0.f;
                PW[q_ * 64 + ((((2 * kq + (li >> 3)) ^ qm) << 3) | (li & 7))] = f2bf(ev);
            }
        }
        asm volatile("s_waitcnt lgkmcnt(0)" ::: "memory");
        const bf16x8 pa0 = *(const bf16x8*)(PW + li * 64 + ((lg ^ (li & 7)) << 3));
        const bf16x8 pa1 = *(const bf16x8*)(PW + li * 64 + (((lg + 4) ^ (li & 7)) << 3));
        __builtin_amdgcn_s_setprio(1);
        #pragma unroll
        for (int nf = 0; nf < 4; ++nf) {
            f32x4 t = __builtin_amdgcn_mfma_f32_16x16x32_bf16(pa0, vf[nf][0], o[nf], 0, 0, 0);
            o[nf] = __builtin_amdgcn_mfma_f32_16x16x32_bf16(pa1, vf[nf][1], t, 0, 0, 0);
        }
        ls = __builtin_amdgcn_mfma_f32_16x16x32_bf16(pa0, ones, ls, 0, 0, 0);
        ls = __builtin_amdgcn_mfma_f32_16x16x32_bf16(pa1, ones, ls, 0, 0, 0);
        __builtin_amdgcn_s_setprio(0);

        __syncthreads();   // prefetch arrived + P/K/V buffer reuse safe
        buf ^= 1;
    }

    #pragma unroll
    for (int nf = 0; nf < 4; ++nf)
        #pragma unroll
        for (int r = 0; r < 4; ++r)
            qp[(size_t)(q0 + lg * 4 + r) * NHD + nf * 16 + li] = f2bf(o[nf][r] / ls[r]);
    #undef STAGE
}

// ---------------------------------------------------------------------------
// Kernel 3: output projection, 128x128 / BK=64, double-buffered issue-early
// staging, XOR-swizzled LDS. A = attn output in q_ws ([B,H,S,HD] permuted).
// ---------------------------------------------------------------------------
template<bool BF>
__global__ __launch_bounds__(256) void out_gemm(
    const u16* __restrict__ Aq,
    const float* __restrict__ Wf, const u16* __restrict__ WbT,
    const float* __restrict__ bias, float* __restrict__ outp)
{
    __shared__ __align__(16) u16 As[2][128 * 64];
    __shared__ __align__(16) u16 Bs[2][128 * 64];

    const int bm = blockIdx.x & 31;
    const int bn = blockIdx.x >> 5;        // 8 N-tiles
    const int m0 = bm * 128, n0 = bn * 128;
    const int tid = threadIdx.x;
    const int lane = tid & 63, wv = tid >> 6;
    const int wm = wv >> 1, wn = wv & 1;
    const int li = lane & 15, lg = lane >> 4;
    const int gsw = ((lane & 7) * 16) ^ ((lane >> 3) << 4);
    const int rsw = (li & 7) << 3;

    f32x4 acc[4][4];
    #pragma unroll
    for (int i = 0; i < 4; ++i)
        #pragma unroll
        for (int j = 0; j < 4; ++j)
            acc[i][j] = (f32x4){0.f, 0.f, 0.f, 0.f};

    auto stage = [&](int B, int k0) {
        const int h = k0 >> 6;
        #pragma unroll
        for (int i = 0; i < 4; ++i) {
            const int r0 = (i * 4 + wv) * 8;
            const int gm = m0 + r0 + (lane >> 3);
            const int b_ = gm >> 11, sI = gm & 2047;
            gload_lds16((const char*)(Aq + (((size_t)(b_ * NH + h)) * NS + sI) * NHD) + gsw,
                        &As[B][r0 * 64]);
            if constexpr (BF)
                gload_lds16((const char*)(WbT + (size_t)(n0 + r0 + (lane >> 3)) * ND + k0) + gsw,
                            &Bs[B][r0 * 64]);
        }
        if constexpr (!BF) {
            #pragma unroll
            for (int i = 0; i < 4; ++i) {
                const int krow = 16 * i + (tid >> 4), ncol = (tid & 15) * 8;
                bf16x8 bv = load8f(Wf + (size_t)(k0 + krow) * ND + n0 + ncol);
                #pragma unroll
                for (int jj = 0; jj < 8; ++jj) {
                    const int n_ = ncol + jj;
                    Bs[B][n_ * 64 + ((((krow >> 3) ^ (n_ & 7)) << 3) | (krow & 7))] = (u16)bv[jj];
                }
            }
        }
    };

    stage(0, 0);
    __syncthreads();

    int buf = 0;
    for (int k0 = 0; k0 < ND; k0 += 64) {
        if (k0 + 64 < ND) stage(buf ^ 1, k0 + 64);

        bf16x8 a[4][2], b[4][2];
        #pragma unroll
        for (int i = 0; i < 4; ++i)
            #pragma unroll
            for (int kk = 0; kk < 2; ++kk)
                a[i][kk] = *(const bf16x8*)(&As[buf][(wm * 64 + i * 16 + li) * 64 + ((kk * 32 + lg * 8) ^ rsw)]);
        #pragma unroll
        for (int j = 0; j < 4; ++j)
            #pragma unroll
            for (int kk = 0; kk < 2; ++kk)
                b[j][kk] = *(const bf16x8*)(&Bs[buf][(wn * 64 + j * 16 + li) * 64 + ((kk * 32 + lg * 8) ^ rsw)]);
        __builtin_amdgcn_s_setprio(1);
        #pragma unroll
        for (int i = 0; i < 4; ++i)
            #pragma unroll
            for (int j = 0; j < 4; ++j) {
                acc[i][j] = __builtin_amdgcn_mfma_f32_16x16x32_bf16(a[i][0], b[j][0], acc[i][j], 0, 0, 0);
                acc[i][j] = __builtin_amdgcn_mfma_f32_16x16x32_bf16(a[i][1], b[j][1], acc[i][j], 0, 0, 0);
            }
        __builtin_amdgcn_s_setprio(0);

        __syncthreads();
        buf ^= 1;
    }

    #pragma unroll
    for (int i = 0; i < 4; ++i) {
      #pragma unroll
      for (int j = 0; j < 4; ++j) {
        const int gn = n0 + wn * 64 + j * 16 + li;
        const float bval = bias[gn];
        #pragma unroll
        for (int r = 0; r < 4; ++r) {
            const int gm = m0 + wm * 64 + i * 16 + lg * 4 + r;
            outp[(size_t)gm * ND + gn] = acc[i][j][r] + bval;
        }
      }
    }
}

// ---------------------------------------------------------------------------
extern "C" void kernel_launch(void* const* d_in, const int* in_sizes, int n_in,
                              void* d_out, int out_size, void* d_ws, size_t ws_size,
                              hipStream_t stream)
{
    const float* X    = (const float*)d_in[0];
    // d_in[1] = causal mask (bool) — deterministic triu(k=1), not read
    const float* Wqkv = (const float*)d_in[2];
    const float* bqkv = (const float*)d_in[3];
    const float* Wout = (const float*)d_in[4];
    const float* bout = (const float*)d_in[5];

    const size_t HE = (size_t)NB * NH * NS * NHD;   // 4,194,304

    float* out  = (float*)d_out;
    float* kout = out + HE;
    float* vout = kout + HE;

    u16* q_ws  = (u16*)d_ws;        // 8 MB: Q bf16 (pre-scaled) -> attn out
    u16* vT_ws = q_ws + HE;         // 8 MB: V^T bf16 [B,H,HD,S]
    u16* k_ws  = vT_ws + HE;        // 8 MB: K bf16 [B,H,S,HD]

    u16* Xb     = k_ws + HE;                    // 8 MB (dead after qkv)
    u16* WqkvT  = Xb + (size_t)NM * ND;         // 6 MB (dead after qkv)
    u16* WoutT  = WqkvT + (size_t)ND * N3;      // 2 MB (live until out_gemm)
    const bool big = ws_size >= (size_t)41943040;   // 40 MB

    if (big) {
        prep_cvt<<<dim3(6144), dim3(256), 0, stream>>>(X, Xb, Wqkv, WqkvT, Wout, WoutT);
        qkv_gemm<true><<<dim3(32 * 24), dim3(256), 0, stream>>>(
            X, Xb, Wqkv, WqkvT, bqkv, q_ws, vT_ws, k_ws, kout, vout);
    } else {
        qkv_gemm<false><<<dim3(32 * 24), dim3(256), 0, stream>>>(
            X, Xb, Wqkv, WqkvT, bqkv, q_ws, vT_ws, k_ws, kout, vout);
    }

    attn_fwd<<<dim3(1024), dim3(256), 0, stream>>>(q_ws, k_ws, vT_ws);

    if (big) {
        out_gemm<true><<<dim3(32 * 8), dim3(256), 0, stream>>>(
            q_ws, Wout, WoutT, bout, out);
    } else {
        out_gemm<false><<<dim3(32 * 8), dim3(256), 0, stream>>>(
            q_ws, Wout, WoutT, bout, out);
    }
}